// Round 9
// baseline (1749.838 us; speedup 1.0000x reference)
//
#include <hip/hip_runtime.h>

#define N_NODES 100000
#define N_EDGES 1600000
#define NL 4
#define NG 1024
#define ZS 68    // LDS z-tile stride (64+4)
#define Z1S 132  // z1l row stride (128+4): spreads row base across banks

// ---------------------------------------------------------------------------
// ws layout (floats):
//   A      @ 0          : N*64   node features. SLICED layout A_t[8][N][8]
//                                (slice s = dims 8s..8s+7; 3.2MB/slice = L2-fit)
//                                except AFTER layer-3 mm2: row-major z2 (for pool)
//   B      @ 6.4M       : N*64   z (pull out, zstats/mm2 in), row-major
//   stats  @ 12.8M      : 17152  [4 x (cs 64 | M 4096) | s2 | q2 | a1 | c1p | a2 | c2]
//   ints   @ ...        : ptr[100001] deg/cursor[100000] csr[1.6M] bs[391]
// ---------------------------------------------------------------------------

__global__ void k_atom_embed(const int* __restrict__ x, const float* __restrict__ emb,
                             float* __restrict__ At) {
  int n = blockIdx.x * 4 + (threadIdx.x >> 6);
  int d = threadIdx.x & 63;
  const int* xr = x + n * 9;
  float acc = 0.f;
#pragma unroll
  for (int c = 0; c < 9; ++c) acc += emb[(c * 100 + xr[c]) * 64 + d];
  At[(size_t)(d >> 3) * N_NODES * 8 + (size_t)n * 8 + (d & 7)] = acc;
}

// ---------------- CSR build (once per call) --------------------------------
__global__ void k_hist(const int* __restrict__ ei, int* __restrict__ deg) {
  int e = blockIdx.x * 256 + threadIdx.x;
  if (e < N_EDGES) atomicAdd(&deg[ei[e]], 1);
}

__global__ void k_scan1(const int* __restrict__ deg, int* __restrict__ bs) {
  __shared__ int s[256];
  int g = blockIdx.x * 256 + threadIdx.x;
  int v = (g < N_NODES) ? deg[g] : 0;
  s[threadIdx.x] = v;
  __syncthreads();
  for (int o = 128; o > 0; o >>= 1) {
    if (threadIdx.x < o) s[threadIdx.x] += s[threadIdx.x + o];
    __syncthreads();
  }
  if (threadIdx.x == 0) bs[blockIdx.x] = s[0];
}

__global__ void k_scan2(int* __restrict__ bs, int nblk) {
  __shared__ int s[512];
  int tid = threadIdx.x;
  int v = (tid < nblk) ? bs[tid] : 0;
  s[tid] = v;
  __syncthreads();
  for (int o = 1; o < 512; o <<= 1) {
    int t = (tid >= o) ? s[tid - o] : 0;
    __syncthreads();
    s[tid] += t;
    __syncthreads();
  }
  if (tid < nblk) bs[tid] = s[tid] - v;  // exclusive
}

__global__ void k_scan3(int* __restrict__ deg, const int* __restrict__ bs,
                        int* __restrict__ ptr) {
  __shared__ int s[256];
  int tid = threadIdx.x;
  int g = blockIdx.x * 256 + tid;
  int v = (g < N_NODES) ? deg[g] : 0;
  s[tid] = v;
  __syncthreads();
  for (int o = 1; o < 256; o <<= 1) {
    int t = (tid >= o) ? s[tid - o] : 0;
    __syncthreads();
    s[tid] += t;
    __syncthreads();
  }
  if (g < N_NODES) {
    int val = bs[blockIdx.x] + s[tid] - v;
    ptr[g] = val;
    deg[g] = val;  // reuse deg as fill cursor
  }
  if (g == 0) ptr[N_NODES] = N_EDGES;
}

__global__ void k_fill(const int* __restrict__ ei, const int* __restrict__ ea,
                       int* __restrict__ cur, unsigned int* __restrict__ csr) {
  int e = blockIdx.x * 256 + threadIdx.x;
  if (e >= N_EDGES) return;
  int s = ei[e];
  unsigned int dst = (unsigned int)ei[N_EDGES + e];
  unsigned int b = (unsigned int)(ea[e * 3] | (ea[e * 3 + 1] << 3) | (ea[e * 3 + 2] << 6));
  int pos = atomicAdd(&cur[s], 1);
  csr[pos] = dst | (b << 17);
}

// ---------------- pull: XCD-sliced gathers ----------------------------------
// Grid = 8 slices x 1563 chunks, slice = bid&7 (matches round-robin block->XCD
// dispatch): slice array (3.2MB) stays resident in that XCD's 4MB L2 -> gathers
// are L2 hits (~200cy) instead of L3 (~600cy). Wave = 8 edge-slots x 8 dims;
// csr entry is an 8-lane broadcast load, no shfl unpack. Output z row-major.
__global__ void __launch_bounds__(256)
k_pull(const float* __restrict__ At, const unsigned int* __restrict__ csr,
       const int* __restrict__ ptr, const float* __restrict__ bond,
       const float* __restrict__ aprev, const float* __restrict__ cprev,
       const float* __restrict__ epsp, int reluf,
       float* __restrict__ z, float* __restrict__ stats0) {
  __shared__ float sb[192];  // 3 tables x 8 vocab x 8 dims (this slice)
  const int s = blockIdx.x & 7, chunk = blockIdx.x >> 3;
  const int j = threadIdx.x & 7, slot = (threadIdx.x >> 3) & 7, wave = threadIdx.x >> 6;
  if (threadIdx.x < 192) {
    int t = threadIdx.x >> 6;        // wrong decomposition avoided: recompute
  }
  for (int i = threadIdx.x; i < 192; i += 256) {
    int tb = i >> 6, rest = i & 63;  // tb 0..2
    int vb = rest >> 3, jj = rest & 7;
    sb[i] = bond[tb * 512 + vb * 64 + s * 8 + jj];
  }
  if (blockIdx.x == 0)
    for (int i = threadIdx.x; i < 16768; i += 256) stats0[i] = 0.f;
  __syncthreads();
  const float ep1 = 1.0f + epsp[0];
  const float aA = reluf ? aprev[s * 8 + j] : 1.0f;
  const float cC = reluf ? cprev[s * 8 + j] : 0.0f;
  const float* As = At + (size_t)s * N_NODES * 8;
#pragma unroll
  for (int g = 0; g < 2; ++g) {
    const int n = chunk * 64 + wave * 16 + g * 8 + slot;
    const bool valid = (n < N_NODES);
    int p0 = 0, len = 0;
    float acc = 0.f;
    if (valid) {
      p0 = ptr[n];
      len = ptr[n + 1] - p0;
      float own = As[(size_t)n * 8 + j];
      if (reluf) own = fmaxf(fmaf(own, aA, cC), 0.f);
      acc = ep1 * own;
    }
    int mlen = len;
    mlen = max(mlen, __shfl_xor(mlen, 8));
    mlen = max(mlen, __shfl_xor(mlen, 16));
    mlen = max(mlen, __shfl_xor(mlen, 32));
    for (int i = 0; i < mlen; ++i) {
      if (i < len) {
        unsigned int pk = csr[p0 + i];  // 8 lanes/slot same addr: broadcast
        unsigned int node = pk & 0x1FFFFu, b = pk >> 17;
        float v = As[(size_t)node * 8 + j];
        if (reluf) v = fmaxf(fmaf(v, aA, cC), 0.f);
        float ef = sb[(b & 7) * 8 + j] + sb[64 + ((b >> 3) & 7) * 8 + j] +
                   sb[128 + (b >> 6) * 8 + j];
        acc += fmaxf(v + ef, 0.f);
      }
    }
    if (valid) z[(size_t)n * 64 + s * 8 + j] = acc;
  }
}

// ---------------- BN1 moments: colsum(z), M = z^T z -------------------------
__global__ void __launch_bounds__(256)
k_zstats(const float* __restrict__ z, float* __restrict__ stats) {
  __shared__ __align__(16) float zl[64 * ZS];
  __shared__ float red[256];
  const int tid = threadIdx.x;
  const int wave = tid >> 6, d = tid & 63;
  const int ar = (tid >> 4) * 4, bc = (tid & 15) * 4;
  float accS = 0.f;
  float m00 = 0.f, m01 = 0.f, m02 = 0.f, m03 = 0.f;
  float m10 = 0.f, m11 = 0.f, m12 = 0.f, m13 = 0.f;
  float m20 = 0.f, m21 = 0.f, m22 = 0.f, m23 = 0.f;
  float m30 = 0.f, m31 = 0.f, m32 = 0.f, m33 = 0.f;
  for (int t = 0; t < 4; ++t) {
    const int nb = (blockIdx.x * 4 + t) * 64;
    const int nlim = N_NODES - nb;
    __syncthreads();
    for (int i = tid; i < 1024; i += 256) {
      int n = i >> 4, k4 = (i & 15) << 2;
      float4 v = make_float4(0.f, 0.f, 0.f, 0.f);
      if (n < nlim) v = *(const float4*)&z[(size_t)(nb + n) * 64 + k4];
      *(float4*)&zl[n * ZS + k4] = v;
    }
    __syncthreads();
#pragma unroll
    for (int ii = 0; ii < 16; ++ii) accS += zl[(wave * 16 + ii) * ZS + d];
#pragma unroll 4
    for (int n = 0; n < 64; ++n) {
      const float4 a = *(const float4*)&zl[n * ZS + ar];
      const float4 b = *(const float4*)&zl[n * ZS + bc];
      m00 = fmaf(a.x, b.x, m00); m01 = fmaf(a.x, b.y, m01); m02 = fmaf(a.x, b.z, m02); m03 = fmaf(a.x, b.w, m03);
      m10 = fmaf(a.y, b.x, m10); m11 = fmaf(a.y, b.y, m11); m12 = fmaf(a.y, b.z, m12); m13 = fmaf(a.y, b.w, m13);
      m20 = fmaf(a.z, b.x, m20); m21 = fmaf(a.z, b.y, m21); m22 = fmaf(a.z, b.z, m22); m23 = fmaf(a.z, b.w, m23);
      m30 = fmaf(a.w, b.x, m30); m31 = fmaf(a.w, b.y, m31); m32 = fmaf(a.w, b.z, m32); m33 = fmaf(a.w, b.w, m33);
    }
  }
  float* copy = stats + (blockIdx.x & 3) * 4160;  // [cs 64 | M 4096]
  red[tid] = accS;
  __syncthreads();
  if (tid < 64)
    atomicAdd(&copy[tid], red[tid] + red[tid + 64] + red[tid + 128] + red[tid + 192]);
  float* M = copy + 64;
  atomicAdd(&M[(ar + 0) * 64 + bc + 0], m00); atomicAdd(&M[(ar + 0) * 64 + bc + 1], m01);
  atomicAdd(&M[(ar + 0) * 64 + bc + 2], m02); atomicAdd(&M[(ar + 0) * 64 + bc + 3], m03);
  atomicAdd(&M[(ar + 1) * 64 + bc + 0], m10); atomicAdd(&M[(ar + 1) * 64 + bc + 1], m11);
  atomicAdd(&M[(ar + 1) * 64 + bc + 2], m12); atomicAdd(&M[(ar + 1) * 64 + bc + 3], m13);
  atomicAdd(&M[(ar + 2) * 64 + bc + 0], m20); atomicAdd(&M[(ar + 2) * 64 + bc + 1], m21);
  atomicAdd(&M[(ar + 2) * 64 + bc + 2], m22); atomicAdd(&M[(ar + 2) * 64 + bc + 3], m23);
  atomicAdd(&M[(ar + 3) * 64 + bc + 0], m30); atomicAdd(&M[(ar + 3) * 64 + bc + 1], m31);
  atomicAdd(&M[(ar + 3) * 64 + bc + 2], m32); atomicAdd(&M[(ar + 3) * 64 + bc + 3], m33);
}

// BN1 params from moments (sums the 4 replicated copies)
__global__ void __launch_bounds__(128, 1)
k_fin1(const float* __restrict__ stats,
       const float* __restrict__ W1, const float* __restrict__ g1,
       const float* __restrict__ be1,
       float* __restrict__ a1, float* __restrict__ c1p) {
  __shared__ float Ml[4096];
  __shared__ float csl[64];
  int j = threadIdx.x;
  for (int i = j; i < 4096; i += 128)
    Ml[i] = stats[64 + i] + stats[4160 + 64 + i] + stats[8320 + 64 + i] + stats[12480 + 64 + i];
  if (j < 64) csl[j] = stats[j] + stats[4160 + j] + stats[8320 + j] + stats[12480 + j];
  __syncthreads();
  float wcol[64];
#pragma unroll
  for (int k = 0; k < 64; ++k) wcol[k] = W1[k * 128 + j];
  float m0 = 0.f;
#pragma unroll
  for (int k = 0; k < 64; ++k) m0 = fmaf(csl[k], wcol[k], m0);
  m0 *= (1.0f / (float)N_NODES);
  float q = 0.f;
  for (int ka = 0; ka < 64; ++ka) {
    const float4* mr = (const float4*)&Ml[ka * 64];
    float t = 0.f;
#pragma unroll
    for (int kb = 0; kb < 16; ++kb) {
      float4 m = mr[kb];
      t = fmaf(m.x, wcol[kb * 4 + 0], t);
      t = fmaf(m.y, wcol[kb * 4 + 1], t);
      t = fmaf(m.z, wcol[kb * 4 + 2], t);
      t = fmaf(m.w, wcol[kb * 4 + 3], t);
    }
    q = fmaf(wcol[ka], t, q);
  }
  float var = q * (1.0f / (float)N_NODES) - m0 * m0;
  float r = rsqrtf(var + 1e-5f);
  float A = g1[j] * r;
  a1[j] = A;
  c1p[j] = fmaf(-m0, A, be1[j]);
}

// fused MLP: z@W1 -> bn1 affine+relu -> z1l (LDS, swizzled) -> @W2 -> z2 + stats2
// LDS trimmed to 49.5KB (z1l overlays zl+w1l head; W2 loaded in 16KB halves)
// -> 3 blocks/CU (round-8: 66KB -> 2 blocks/CU, 17% occupancy).
// z1l stride 132 spreads row base across banks (write conflict 8-way -> 4-way).
__global__ void __launch_bounds__(256, 3)
k_mm2(const float* __restrict__ z, const float* __restrict__ W1g,
      const float* __restrict__ a1, const float* __restrict__ c1p,
      const float* __restrict__ W2g, const float* __restrict__ b2,
      float* __restrict__ zout, int sliced,
      float* __restrict__ s2, float* __restrict__ q2) {
  __shared__ __align__(16) float sm[12672];
  float* zl = sm;            // [64][68]  phase A          (0..4352)
  float* w1l = sm + 4352;    // [64][128] phase A          (4352..12544)
  float* z1l = sm;           // [64][132] phase B, overlays (0..8448)
  float* w2l = sm + 8448;    // [64][64] half of W2        (8448..12544)
  float* ss = sm + 12544;
  float* sq = sm + 12608;
  int tid = threadIdx.x;
  int nb = blockIdx.x * 64;
  int nlim = N_NODES - nb;
  if (tid < 128) sm[12544 + tid] = 0.f;
  for (int i = tid; i < 1024; i += 256) {
    int n = i >> 4, k4 = (i & 15) << 2;
    float4 v = make_float4(0.f, 0.f, 0.f, 0.f);
    if (n < nlim) v = *(const float4*)&z[(size_t)(nb + n) * 64 + k4];
    *(float4*)&zl[n * ZS + k4] = v;
  }
  for (int i = tid; i < 2048; i += 256)
    *(float4*)&w1l[i * 4] = *(const float4*)&W1g[i * 4];
  __syncthreads();

  const int jg = tid & 15, ng = tid >> 4;
  const int n0 = ng * 4;
  float acc[4][8];
#pragma unroll
  for (int i = 0; i < 4; ++i)
#pragma unroll
    for (int c = 0; c < 8; ++c) acc[i][c] = 0.f;
#pragma unroll 2
  for (int k4 = 0; k4 < 16; ++k4) {
    float4 za[4];
#pragma unroll
    for (int i = 0; i < 4; ++i) za[i] = *(const float4*)&zl[(n0 + i) * ZS + k4 * 4];
#pragma unroll
    for (int kk = 0; kk < 4; ++kk) {
      const float4 w0 = *(const float4*)&w1l[(k4 * 4 + kk) * 128 + jg * 4];
      const float4 w1 = *(const float4*)&w1l[(k4 * 4 + kk) * 128 + 64 + jg * 4];
#pragma unroll
      for (int i = 0; i < 4; ++i) {
        const float zv = ((const float*)&za[i])[kk];
        acc[i][0] = fmaf(zv, w0.x, acc[i][0]);
        acc[i][1] = fmaf(zv, w0.y, acc[i][1]);
        acc[i][2] = fmaf(zv, w0.z, acc[i][2]);
        acc[i][3] = fmaf(zv, w0.w, acc[i][3]);
        acc[i][4] = fmaf(zv, w1.x, acc[i][4]);
        acc[i][5] = fmaf(zv, w1.y, acc[i][5]);
        acc[i][6] = fmaf(zv, w1.z, acc[i][6]);
        acc[i][7] = fmaf(zv, w1.w, acc[i][7]);
      }
    }
  }
  const float4 av0 = *(const float4*)&a1[jg * 4], av1 = *(const float4*)&a1[64 + jg * 4];
  const float4 cv0 = *(const float4*)&c1p[jg * 4], cv1 = *(const float4*)&c1p[64 + jg * 4];
  __syncthreads();  // zl/w1l reads done; accs in regs; safe to overlay
  const int sxor = ng & 7;
#pragma unroll
  for (int i = 0; i < 4; ++i) {
    float4 v0, v1;
    v0.x = fmaxf(fmaf(acc[i][0], av0.x, cv0.x), 0.f);
    v0.y = fmaxf(fmaf(acc[i][1], av0.y, cv0.y), 0.f);
    v0.z = fmaxf(fmaf(acc[i][2], av0.z, cv0.z), 0.f);
    v0.w = fmaxf(fmaf(acc[i][3], av0.w, cv0.w), 0.f);
    v1.x = fmaxf(fmaf(acc[i][4], av1.x, cv1.x), 0.f);
    v1.y = fmaxf(fmaf(acc[i][5], av1.y, cv1.y), 0.f);
    v1.z = fmaxf(fmaf(acc[i][6], av1.z, cv1.z), 0.f);
    v1.w = fmaxf(fmaf(acc[i][7], av1.w, cv1.w), 0.f);
    const int g0 = jg ^ sxor, g1i = 16 + (jg ^ sxor);
    *(float4*)&z1l[(n0 + i) * Z1S + g0 * 4] = v0;
    *(float4*)&z1l[(n0 + i) * Z1S + g1i * 4] = v1;
  }

  const int jb = (tid & 7) * 8, n0b = (tid >> 3) * 2;
  const float4 b20 = *(const float4*)&b2[jb], b21 = *(const float4*)&b2[jb + 4];
  float accB[2][8];
#pragma unroll
  for (int i = 0; i < 2; ++i) {
    accB[i][0] = b20.x; accB[i][1] = b20.y; accB[i][2] = b20.z; accB[i][3] = b20.w;
    accB[i][4] = b21.x; accB[i][5] = b21.y; accB[i][6] = b21.z; accB[i][7] = b21.w;
  }
#pragma unroll
  for (int kc = 0; kc < 2; ++kc) {
    __syncthreads();  // kc=0: z1l writes done; kc=1: w2l half0 reads done
    for (int i = tid; i < 1024; i += 256)
      *(float4*)&w2l[i * 4] = *(const float4*)&W2g[kc * 4096 + i * 4];
    __syncthreads();
#pragma unroll 2
    for (int k4 = 0; k4 < 16; ++k4) {
      const int kg = kc * 16 + k4;
      float4 zb[2];
#pragma unroll
      for (int i = 0; i < 2; ++i) {
        const int n = n0b + i;
        const int gs = kg ^ ((n >> 2) & 7);
        zb[i] = *(const float4*)&z1l[n * Z1S + gs * 4];
      }
#pragma unroll
      for (int kk = 0; kk < 4; ++kk) {
        const float4 w0 = *(const float4*)&w2l[(k4 * 4 + kk) * 64 + jb];
        const float4 w1 = *(const float4*)&w2l[(k4 * 4 + kk) * 64 + jb + 4];
#pragma unroll
        for (int i = 0; i < 2; ++i) {
          const float zv = ((const float*)&zb[i])[kk];
          accB[i][0] = fmaf(zv, w0.x, accB[i][0]);
          accB[i][1] = fmaf(zv, w0.y, accB[i][1]);
          accB[i][2] = fmaf(zv, w0.z, accB[i][2]);
          accB[i][3] = fmaf(zv, w0.w, accB[i][3]);
          accB[i][4] = fmaf(zv, w1.x, accB[i][4]);
          accB[i][5] = fmaf(zv, w1.y, accB[i][5]);
          accB[i][6] = fmaf(zv, w1.z, accB[i][6]);
          accB[i][7] = fmaf(zv, w1.w, accB[i][7]);
        }
      }
    }
  }
  float sj[8], qj[8];
#pragma unroll
  for (int c = 0; c < 8; ++c) { sj[c] = 0.f; qj[c] = 0.f; }
#pragma unroll
  for (int i = 0; i < 2; ++i) {
    const int n = n0b + i;
    if (n < nlim) {
      float4 o0, o1;
      o0.x = accB[i][0]; o0.y = accB[i][1]; o0.z = accB[i][2]; o0.w = accB[i][3];
      o1.x = accB[i][4]; o1.y = accB[i][5]; o1.z = accB[i][6]; o1.w = accB[i][7];
      if (sliced) {
        float* dst = zout + (size_t)(jb >> 3) * N_NODES * 8 + (size_t)(nb + n) * 8;
        *(float4*)dst = o0;
        *(float4*)(dst + 4) = o1;
      } else {
        *(float4*)&zout[(size_t)(nb + n) * 64 + jb] = o0;
        *(float4*)&zout[(size_t)(nb + n) * 64 + jb + 4] = o1;
      }
#pragma unroll
      for (int c = 0; c < 8; ++c) {
        sj[c] += accB[i][c];
        qj[c] = fmaf(accB[i][c], accB[i][c], qj[c]);
      }
    }
  }
#pragma unroll
  for (int c = 0; c < 8; ++c) {
    atomicAdd(&ss[jb + c], sj[c]);
    atomicAdd(&sq[jb + c], qj[c]);
  }
  __syncthreads();
  if (tid < 64) {
    atomicAdd(&s2[tid], ss[tid]);
    atomicAdd(&q2[tid], sq[tid]);
  }
}

__global__ void k_finalize(const float* __restrict__ sum, const float* __restrict__ sq,
                           const float* __restrict__ g, const float* __restrict__ b,
                           float* __restrict__ a, float* __restrict__ c) {
  int j = threadIdx.x;
  const float inv = 1.0f / (float)N_NODES;
  float m = sum[j] * inv;
  float v = sq[j] * inv - m * m;
  float r = rsqrtf(v + 1e-5f);
  float aa = g[j] * r;
  a[j] = aa;
  c[j] = fmaf(-m, aa, b[j]);
}

// ---------------- pool: batch sorted -> one wave per graph, zero atomics ----
// reads the (row-major) z2 written by layer-3 mm2
__global__ void __launch_bounds__(256)
k_pool(const float* __restrict__ z2, const float* __restrict__ a2,
       const float* __restrict__ c2, const int* __restrict__ batch,
       float* __restrict__ out) {
  int g = blockIdx.x * 4 + (threadIdx.x >> 6);
  int d = threadIdx.x & 63;
  int a = 0, b = N_NODES;
  while (a < b) { int m = (a + b) >> 1; if (batch[m] < g) a = m + 1; else b = m; }
  const int lo = a;
  b = N_NODES;
  while (a < b) { int m = (a + b) >> 1; if (batch[m] < g + 1) a = m + 1; else b = m; }
  const int hi = a;
  float s0 = 0.f, s1 = 0.f, s2 = 0.f, s3 = 0.f;
  int n = lo;
  for (; n + 4 <= hi; n += 4) {
    s0 += z2[(size_t)(n + 0) * 64 + d];
    s1 += z2[(size_t)(n + 1) * 64 + d];
    s2 += z2[(size_t)(n + 2) * 64 + d];
    s3 += z2[(size_t)(n + 3) * 64 + d];
  }
  for (; n < hi; ++n) s0 += z2[(size_t)n * 64 + d];
  float S = (s0 + s1) + (s2 + s3);
  float cntf = (float)(hi - lo);
  out[g * 64 + d] = fmaf(S, a2[d], cntf * c2[d]) / (cntf + 1e-9f);
}

extern "C" void kernel_launch(void* const* d_in, const int* in_sizes, int n_in,
                              void* d_out, int out_size, void* d_ws, size_t ws_size,
                              hipStream_t stream) {
  const int* x = (const int*)d_in[0];
  const int* ea = (const int*)d_in[1];
  const int* ei = (const int*)d_in[2];
  const int* batch = (const int*)d_in[3];
  const float* atom_emb = (const float*)d_in[4];
  const float* bond_emb = (const float*)d_in[5];
  const float* W1 = (const float*)d_in[6];
  const float* g1 = (const float*)d_in[8];
  const float* be1 = (const float*)d_in[9];
  const float* W2 = (const float*)d_in[10];
  const float* b2 = (const float*)d_in[11];
  const float* eps = (const float*)d_in[12];
  const float* bn_g = (const float*)d_in[13];
  const float* bn_b = (const float*)d_in[14];

  float* w = (float*)d_ws;
  float* A = w;                                 // sliced A_t; row-major z2 after l=3
  float* B = w + (size_t)N_NODES * 64;
  float* stats = B + (size_t)N_NODES * 64;      // 4x(cs|M) = 16640
  float* s2 = stats + 16640;
  float* q2 = stats + 16704;
  float* a1 = stats + 16768;
  float* c1p = stats + 16896;
  float* a2 = stats + 17024;
  float* c2 = stats + 17088;
  int* ptr = (int*)(stats + 17152);             // 100001
  int* deg = ptr + (N_NODES + 1);               // 100000
  unsigned int* csr = (unsigned int*)(deg + N_NODES);  // 1.6M
  int* bs = (int*)(csr + N_EDGES);              // 391

  const int NBLK = (N_NODES + 255) / 256;   // 391
  const int NTILE = (N_NODES + 63) / 64;    // 1563
  const int NPULL = 8 * NTILE;              // 12504 (8 slices x 1563 chunks)
  const int NZ = NBLK;                      // 391

  hipMemsetAsync(deg, 0, N_NODES * sizeof(int), stream);

  k_atom_embed<<<N_NODES / 4, 256, 0, stream>>>(x, atom_emb, A);

  // CSR build (once; reused across all 4 layers)
  k_hist<<<(N_EDGES + 255) / 256, 256, 0, stream>>>(ei, deg);
  k_scan1<<<NBLK, 256, 0, stream>>>(deg, bs);
  k_scan2<<<1, 512, 0, stream>>>(bs, NBLK);
  k_scan3<<<NBLK, 256, 0, stream>>>(deg, bs, ptr);
  k_fill<<<(N_EDGES + 255) / 256, 256, 0, stream>>>(ei, ea, deg, csr);

  for (int l = 0; l < NL; ++l) {
    k_pull<<<NPULL, 256, 0, stream>>>(
        A, csr, ptr, bond_emb + (size_t)l * 1536, a2, c2, eps + l,
        (l > 0) ? 1 : 0, B, stats);
    k_zstats<<<NZ, 256, 0, stream>>>(B, stats);
    k_fin1<<<1, 128, 0, stream>>>(stats, W1 + (size_t)l * 8192,
                                  g1 + l * 128, be1 + l * 128, a1, c1p);
    k_mm2<<<NTILE, 256, 0, stream>>>(
        B, W1 + (size_t)l * 8192, a1, c1p, W2 + (size_t)l * 8192, b2 + l * 64,
        A, (l < NL - 1) ? 1 : 0, s2, q2);
    k_finalize<<<1, 64, 0, stream>>>(s2, q2, bn_g + l * 64, bn_b + l * 64, a2, c2);
  }
  k_pool<<<NG / 4, 256, 0, stream>>>(A, a2, c2, batch, (float*)d_out);
}

// Round 10
// 1281.148 us; speedup vs baseline: 1.3658x; 1.3658x over previous
//
#include <hip/hip_runtime.h>

#define N_NODES 100000
#define N_EDGES 1600000
#define NL 4
#define NG 1024
#define ZS 68    // LDS z-tile stride (64+4)
#define Z1S 132  // z1l row stride (128+4)

// ---------------------------------------------------------------------------
// ws layout (floats):
//   A      @ 0          : N*64   h0 / z2 (row-major)
//   B      @ 6.4M       : N*64   z (pull out, zstats/mm2 in)
//   stats  @ 12.8M      : 17152  [4 x (cs 64 | M 4096) | s2 | q2 | a1 | c1p | a2 | c2]
//   ints   @ ...        : ptr[100001] deg/cursor[100000] csr[1.6M] bs[391]
// ---------------------------------------------------------------------------

__global__ void k_atom_embed(const int* __restrict__ x, const float* __restrict__ emb,
                             float* __restrict__ h) {
  int n = blockIdx.x * 4 + (threadIdx.x >> 6);
  int d = threadIdx.x & 63;
  const int* xr = x + n * 9;
  float acc = 0.f;
#pragma unroll
  for (int c = 0; c < 9; ++c) acc += emb[(c * 100 + xr[c]) * 64 + d];
  h[n * 64 + d] = acc;
}

// ---------------- CSR build (once per call) --------------------------------
__global__ void k_hist(const int* __restrict__ ei, int* __restrict__ deg) {
  int e = blockIdx.x * 256 + threadIdx.x;
  if (e < N_EDGES) atomicAdd(&deg[ei[e]], 1);
}

__global__ void k_scan1(const int* __restrict__ deg, int* __restrict__ bs) {
  __shared__ int s[256];
  int g = blockIdx.x * 256 + threadIdx.x;
  int v = (g < N_NODES) ? deg[g] : 0;
  s[threadIdx.x] = v;
  __syncthreads();
  for (int o = 128; o > 0; o >>= 1) {
    if (threadIdx.x < o) s[threadIdx.x] += s[threadIdx.x + o];
    __syncthreads();
  }
  if (threadIdx.x == 0) bs[blockIdx.x] = s[0];
}

__global__ void k_scan2(int* __restrict__ bs, int nblk) {
  __shared__ int s[512];
  int tid = threadIdx.x;
  int v = (tid < nblk) ? bs[tid] : 0;
  s[tid] = v;
  __syncthreads();
  for (int o = 1; o < 512; o <<= 1) {
    int t = (tid >= o) ? s[tid - o] : 0;
    __syncthreads();
    s[tid] += t;
    __syncthreads();
  }
  if (tid < nblk) bs[tid] = s[tid] - v;  // exclusive
}

__global__ void k_scan3(int* __restrict__ deg, const int* __restrict__ bs,
                        int* __restrict__ ptr) {
  __shared__ int s[256];
  int tid = threadIdx.x;
  int g = blockIdx.x * 256 + tid;
  int v = (g < N_NODES) ? deg[g] : 0;
  s[tid] = v;
  __syncthreads();
  for (int o = 1; o < 256; o <<= 1) {
    int t = (tid >= o) ? s[tid - o] : 0;
    __syncthreads();
    s[tid] += t;
    __syncthreads();
  }
  if (g < N_NODES) {
    int val = bs[blockIdx.x] + s[tid] - v;
    ptr[g] = val;
    deg[g] = val;  // reuse deg as fill cursor
  }
  if (g == 0) ptr[N_NODES] = N_EDGES;
}

__global__ void k_fill(const int* __restrict__ ei, const int* __restrict__ ea,
                       int* __restrict__ cur, unsigned int* __restrict__ csr) {
  int e = blockIdx.x * 256 + threadIdx.x;
  if (e >= N_EDGES) return;
  int s = ei[e];
  unsigned int dst = (unsigned int)ei[N_EDGES + e];
  unsigned int b = (unsigned int)(ea[e * 3] | (ea[e * 3 + 1] << 3) | (ea[e * 3 + 2] << 6));
  int pos = atomicAdd(&cur[s], 1);
  csr[pos] = dst | (b << 17);
}

// ---------------- pull-mode aggregation (round-8 structure, 8-deep unroll) --
// wave = one node's 64 dims; csr chunk coalesced-loaded + shfl broadcast;
// 8 outstanding gathers per iter (round-9 slot-slicing regressed: 8x csr
// traffic + divergence + serial gathers; reverted).
__global__ void __launch_bounds__(256)
k_pull(const float* __restrict__ src, const unsigned int* __restrict__ csr,
       const int* __restrict__ ptr, const float* __restrict__ bond,
       const float* __restrict__ aprev, const float* __restrict__ cprev,
       const float* __restrict__ epsp, int reluf,
       float* __restrict__ z, float* __restrict__ stats0) {
  __shared__ float sb[1536];
  for (int i = threadIdx.x; i < 1536; i += 256) sb[i] = bond[i];
  if (blockIdx.x == 0)
    for (int i = threadIdx.x; i < 16768; i += 256) stats0[i] = 0.f;
  __syncthreads();
  const int wave = threadIdx.x >> 6, d = threadIdx.x & 63;
  const float ep1 = 1.0f + epsp[0];
  const float aA = reluf ? aprev[d] : 1.0f;
  const float cC = reluf ? cprev[d] : 0.0f;
  const int n0 = blockIdx.x * 32 + wave * 8;
#pragma unroll
  for (int ii = 0; ii < 8; ++ii) {
    int n = n0 + ii;
    int p0 = ptr[n], p1 = ptr[n + 1];
    float own = src[(size_t)n * 64 + d];
    if (reluf) own = fmaxf(fmaf(own, aA, cC), 0.f);
    float acc = ep1 * own;
    for (int base = p0; base < p1; base += 64) {
      int cnt = min(64, p1 - base);
      unsigned int mypk = (d < cnt) ? csr[base + d] : 0u;
      int i = 0;
      for (; i + 8 <= cnt; i += 8) {
        unsigned int pk[8];
        float v[8];
#pragma unroll
        for (int u = 0; u < 8; ++u) pk[u] = __shfl(mypk, i + u);
#pragma unroll
        for (int u = 0; u < 8; ++u) v[u] = src[(size_t)(pk[u] & 0x1FFFFu) * 64 + d];
#pragma unroll
        for (int u = 0; u < 8; ++u) {
          if (reluf) v[u] = fmaxf(fmaf(v[u], aA, cC), 0.f);
          unsigned int b = pk[u] >> 17;
          float ef = sb[(b & 7) * 64 + d] + sb[(((b >> 3) & 7) + 8) * 64 + d] +
                     sb[((b >> 6) + 16) * 64 + d];
          acc += fmaxf(v[u] + ef, 0.f);
        }
      }
      for (; i < cnt; ++i) {
        unsigned int pk = __shfl(mypk, i);
        float v = src[(size_t)(pk & 0x1FFFFu) * 64 + d];
        if (reluf) v = fmaxf(fmaf(v, aA, cC), 0.f);
        unsigned int b = pk >> 17;
        float ef = sb[(b & 7) * 64 + d] + sb[(((b >> 3) & 7) + 8) * 64 + d] +
                   sb[((b >> 6) + 16) * 64 + d];
        acc += fmaxf(v + ef, 0.f);
      }
    }
    z[(size_t)n * 64 + d] = acc;
  }
}

// ---------------- BN1 moments: colsum(z), M = z^T z -------------------------
__global__ void __launch_bounds__(256)
k_zstats(const float* __restrict__ z, float* __restrict__ stats) {
  __shared__ __align__(16) float zl[64 * ZS];
  __shared__ float red[256];
  const int tid = threadIdx.x;
  const int wave = tid >> 6, d = tid & 63;
  const int ar = (tid >> 4) * 4, bc = (tid & 15) * 4;
  float accS = 0.f;
  float m00 = 0.f, m01 = 0.f, m02 = 0.f, m03 = 0.f;
  float m10 = 0.f, m11 = 0.f, m12 = 0.f, m13 = 0.f;
  float m20 = 0.f, m21 = 0.f, m22 = 0.f, m23 = 0.f;
  float m30 = 0.f, m31 = 0.f, m32 = 0.f, m33 = 0.f;
  for (int t = 0; t < 4; ++t) {
    const int nb = (blockIdx.x * 4 + t) * 64;
    const int nlim = N_NODES - nb;
    __syncthreads();
    for (int i = tid; i < 1024; i += 256) {
      int n = i >> 4, k4 = (i & 15) << 2;
      float4 v = make_float4(0.f, 0.f, 0.f, 0.f);
      if (n < nlim) v = *(const float4*)&z[(size_t)(nb + n) * 64 + k4];
      *(float4*)&zl[n * ZS + k4] = v;
    }
    __syncthreads();
#pragma unroll
    for (int ii = 0; ii < 16; ++ii) accS += zl[(wave * 16 + ii) * ZS + d];
#pragma unroll 4
    for (int n = 0; n < 64; ++n) {
      const float4 a = *(const float4*)&zl[n * ZS + ar];
      const float4 b = *(const float4*)&zl[n * ZS + bc];
      m00 = fmaf(a.x, b.x, m00); m01 = fmaf(a.x, b.y, m01); m02 = fmaf(a.x, b.z, m02); m03 = fmaf(a.x, b.w, m03);
      m10 = fmaf(a.y, b.x, m10); m11 = fmaf(a.y, b.y, m11); m12 = fmaf(a.y, b.z, m12); m13 = fmaf(a.y, b.w, m13);
      m20 = fmaf(a.z, b.x, m20); m21 = fmaf(a.z, b.y, m21); m22 = fmaf(a.z, b.z, m22); m23 = fmaf(a.z, b.w, m23);
      m30 = fmaf(a.w, b.x, m30); m31 = fmaf(a.w, b.y, m31); m32 = fmaf(a.w, b.z, m32); m33 = fmaf(a.w, b.w, m33);
    }
  }
  float* copy = stats + (blockIdx.x & 3) * 4160;  // [cs 64 | M 4096]
  red[tid] = accS;
  __syncthreads();
  if (tid < 64)
    atomicAdd(&copy[tid], red[tid] + red[tid + 64] + red[tid + 128] + red[tid + 192]);
  float* M = copy + 64;
  atomicAdd(&M[(ar + 0) * 64 + bc + 0], m00); atomicAdd(&M[(ar + 0) * 64 + bc + 1], m01);
  atomicAdd(&M[(ar + 0) * 64 + bc + 2], m02); atomicAdd(&M[(ar + 0) * 64 + bc + 3], m03);
  atomicAdd(&M[(ar + 1) * 64 + bc + 0], m10); atomicAdd(&M[(ar + 1) * 64 + bc + 1], m11);
  atomicAdd(&M[(ar + 1) * 64 + bc + 2], m12); atomicAdd(&M[(ar + 1) * 64 + bc + 3], m13);
  atomicAdd(&M[(ar + 2) * 64 + bc + 0], m20); atomicAdd(&M[(ar + 2) * 64 + bc + 1], m21);
  atomicAdd(&M[(ar + 2) * 64 + bc + 2], m22); atomicAdd(&M[(ar + 2) * 64 + bc + 3], m23);
  atomicAdd(&M[(ar + 3) * 64 + bc + 0], m30); atomicAdd(&M[(ar + 3) * 64 + bc + 1], m31);
  atomicAdd(&M[(ar + 3) * 64 + bc + 2], m32); atomicAdd(&M[(ar + 3) * 64 + bc + 3], m33);
}

// BN1 params from moments (sums the 4 replicated copies)
__global__ void __launch_bounds__(128, 1)
k_fin1(const float* __restrict__ stats,
       const float* __restrict__ W1, const float* __restrict__ g1,
       const float* __restrict__ be1,
       float* __restrict__ a1, float* __restrict__ c1p) {
  __shared__ float Ml[4096];
  __shared__ float csl[64];
  int j = threadIdx.x;
  for (int i = j; i < 4096; i += 128)
    Ml[i] = stats[64 + i] + stats[4160 + 64 + i] + stats[8320 + 64 + i] + stats[12480 + 64 + i];
  if (j < 64) csl[j] = stats[j] + stats[4160 + j] + stats[8320 + j] + stats[12480 + j];
  __syncthreads();
  float wcol[64];
#pragma unroll
  for (int k = 0; k < 64; ++k) wcol[k] = W1[k * 128 + j];
  float m0 = 0.f;
#pragma unroll
  for (int k = 0; k < 64; ++k) m0 = fmaf(csl[k], wcol[k], m0);
  m0 *= (1.0f / (float)N_NODES);
  float q = 0.f;
  for (int ka = 0; ka < 64; ++ka) {
    const float4* mr = (const float4*)&Ml[ka * 64];
    float t = 0.f;
#pragma unroll
    for (int kb = 0; kb < 16; ++kb) {
      float4 m = mr[kb];
      t = fmaf(m.x, wcol[kb * 4 + 0], t);
      t = fmaf(m.y, wcol[kb * 4 + 1], t);
      t = fmaf(m.z, wcol[kb * 4 + 2], t);
      t = fmaf(m.w, wcol[kb * 4 + 3], t);
    }
    q = fmaf(wcol[ka], t, q);
  }
  float var = q * (1.0f / (float)N_NODES) - m0 * m0;
  float r = rsqrtf(var + 1e-5f);
  float A = g1[j] * r;
  a1[j] = A;
  c1p[j] = fmaf(-m0, A, be1[j]);
}

// fused MLP: z@W1 -> bn1 affine+relu -> z1l (LDS) -> @W2 -> z2 + stats2
// 49.5KB LDS (z1l overlays phase-A head; W2 in two 16KB halves) -> 3 blocks/CU
__global__ void __launch_bounds__(256, 3)
k_mm2(const float* __restrict__ z, const float* __restrict__ W1g,
      const float* __restrict__ a1, const float* __restrict__ c1p,
      const float* __restrict__ W2g, const float* __restrict__ b2,
      float* __restrict__ zout, float* __restrict__ s2, float* __restrict__ q2) {
  __shared__ __align__(16) float sm[12672];
  float* zl = sm;            // [64][68]  phase A          (0..4352)
  float* w1l = sm + 4352;    // [64][128] phase A          (4352..12544)
  float* z1l = sm;           // [64][132] phase B, overlays (0..8448)
  float* w2l = sm + 8448;    // [64][64] half of W2        (8448..12544)
  float* ss = sm + 12544;
  float* sq = sm + 12608;
  int tid = threadIdx.x;
  int nb = blockIdx.x * 64;
  int nlim = N_NODES - nb;
  if (tid < 128) sm[12544 + tid] = 0.f;
  for (int i = tid; i < 1024; i += 256) {
    int n = i >> 4, k4 = (i & 15) << 2;
    float4 v = make_float4(0.f, 0.f, 0.f, 0.f);
    if (n < nlim) v = *(const float4*)&z[(size_t)(nb + n) * 64 + k4];
    *(float4*)&zl[n * ZS + k4] = v;
  }
  for (int i = tid; i < 2048; i += 256)
    *(float4*)&w1l[i * 4] = *(const float4*)&W1g[i * 4];
  __syncthreads();

  const int jg = tid & 15, ng = tid >> 4;
  const int n0 = ng * 4;
  float acc[4][8];
#pragma unroll
  for (int i = 0; i < 4; ++i)
#pragma unroll
    for (int c = 0; c < 8; ++c) acc[i][c] = 0.f;
#pragma unroll 2
  for (int k4 = 0; k4 < 16; ++k4) {
    float4 za[4];
#pragma unroll
    for (int i = 0; i < 4; ++i) za[i] = *(const float4*)&zl[(n0 + i) * ZS + k4 * 4];
#pragma unroll
    for (int kk = 0; kk < 4; ++kk) {
      const float4 w0 = *(const float4*)&w1l[(k4 * 4 + kk) * 128 + jg * 4];
      const float4 w1 = *(const float4*)&w1l[(k4 * 4 + kk) * 128 + 64 + jg * 4];
#pragma unroll
      for (int i = 0; i < 4; ++i) {
        const float zv = ((const float*)&za[i])[kk];
        acc[i][0] = fmaf(zv, w0.x, acc[i][0]);
        acc[i][1] = fmaf(zv, w0.y, acc[i][1]);
        acc[i][2] = fmaf(zv, w0.z, acc[i][2]);
        acc[i][3] = fmaf(zv, w0.w, acc[i][3]);
        acc[i][4] = fmaf(zv, w1.x, acc[i][4]);
        acc[i][5] = fmaf(zv, w1.y, acc[i][5]);
        acc[i][6] = fmaf(zv, w1.z, acc[i][6]);
        acc[i][7] = fmaf(zv, w1.w, acc[i][7]);
      }
    }
  }
  const float4 av0 = *(const float4*)&a1[jg * 4], av1 = *(const float4*)&a1[64 + jg * 4];
  const float4 cv0 = *(const float4*)&c1p[jg * 4], cv1 = *(const float4*)&c1p[64 + jg * 4];
  __syncthreads();  // zl/w1l reads done; accs in regs; safe to overlay
  const int sxor = ng & 7;
#pragma unroll
  for (int i = 0; i < 4; ++i) {
    float4 v0, v1;
    v0.x = fmaxf(fmaf(acc[i][0], av0.x, cv0.x), 0.f);
    v0.y = fmaxf(fmaf(acc[i][1], av0.y, cv0.y), 0.f);
    v0.z = fmaxf(fmaf(acc[i][2], av0.z, cv0.z), 0.f);
    v0.w = fmaxf(fmaf(acc[i][3], av0.w, cv0.w), 0.f);
    v1.x = fmaxf(fmaf(acc[i][4], av1.x, cv1.x), 0.f);
    v1.y = fmaxf(fmaf(acc[i][5], av1.y, cv1.y), 0.f);
    v1.z = fmaxf(fmaf(acc[i][6], av1.z, cv1.z), 0.f);
    v1.w = fmaxf(fmaf(acc[i][7], av1.w, cv1.w), 0.f);
    const int g0 = jg ^ sxor, g1i = 16 + (jg ^ sxor);
    *(float4*)&z1l[(n0 + i) * Z1S + g0 * 4] = v0;
    *(float4*)&z1l[(n0 + i) * Z1S + g1i * 4] = v1;
  }

  const int jb = (tid & 7) * 8, n0b = (tid >> 3) * 2;
  const float4 b20 = *(const float4*)&b2[jb], b21 = *(const float4*)&b2[jb + 4];
  float accB[2][8];
#pragma unroll
  for (int i = 0; i < 2; ++i) {
    accB[i][0] = b20.x; accB[i][1] = b20.y; accB[i][2] = b20.z; accB[i][3] = b20.w;
    accB[i][4] = b21.x; accB[i][5] = b21.y; accB[i][6] = b21.z; accB[i][7] = b21.w;
  }
#pragma unroll
  for (int kc = 0; kc < 2; ++kc) {
    __syncthreads();  // kc=0: z1l writes done; kc=1: w2l half0 reads done
    for (int i = tid; i < 1024; i += 256)
      *(float4*)&w2l[i * 4] = *(const float4*)&W2g[kc * 4096 + i * 4];
    __syncthreads();
#pragma unroll 2
    for (int k4 = 0; k4 < 16; ++k4) {
      const int kg = kc * 16 + k4;
      float4 zb[2];
#pragma unroll
      for (int i = 0; i < 2; ++i) {
        const int n = n0b + i;
        const int gs = kg ^ ((n >> 2) & 7);
        zb[i] = *(const float4*)&z1l[n * Z1S + gs * 4];
      }
#pragma unroll
      for (int kk = 0; kk < 4; ++kk) {
        const float4 w0 = *(const float4*)&w2l[(k4 * 4 + kk) * 64 + jb];
        const float4 w1 = *(const float4*)&w2l[(k4 * 4 + kk) * 64 + jb + 4];
#pragma unroll
        for (int i = 0; i < 2; ++i) {
          const float zv = ((const float*)&zb[i])[kk];
          accB[i][0] = fmaf(zv, w0.x, accB[i][0]);
          accB[i][1] = fmaf(zv, w0.y, accB[i][1]);
          accB[i][2] = fmaf(zv, w0.z, accB[i][2]);
          accB[i][3] = fmaf(zv, w0.w, accB[i][3]);
          accB[i][4] = fmaf(zv, w1.x, accB[i][4]);
          accB[i][5] = fmaf(zv, w1.y, accB[i][5]);
          accB[i][6] = fmaf(zv, w1.z, accB[i][6]);
          accB[i][7] = fmaf(zv, w1.w, accB[i][7]);
        }
      }
    }
  }
  float sj[8], qj[8];
#pragma unroll
  for (int c = 0; c < 8; ++c) { sj[c] = 0.f; qj[c] = 0.f; }
#pragma unroll
  for (int i = 0; i < 2; ++i) {
    const int n = n0b + i;
    if (n < nlim) {
      float4 o0, o1;
      o0.x = accB[i][0]; o0.y = accB[i][1]; o0.z = accB[i][2]; o0.w = accB[i][3];
      o1.x = accB[i][4]; o1.y = accB[i][5]; o1.z = accB[i][6]; o1.w = accB[i][7];
      *(float4*)&zout[(size_t)(nb + n) * 64 + jb] = o0;
      *(float4*)&zout[(size_t)(nb + n) * 64 + jb + 4] = o1;
#pragma unroll
      for (int c = 0; c < 8; ++c) {
        sj[c] += accB[i][c];
        qj[c] = fmaf(accB[i][c], accB[i][c], qj[c]);
      }
    }
  }
#pragma unroll
  for (int c = 0; c < 8; ++c) {
    atomicAdd(&ss[jb + c], sj[c]);
    atomicAdd(&sq[jb + c], qj[c]);
  }
  __syncthreads();
  if (tid < 64) {
    atomicAdd(&s2[tid], ss[tid]);
    atomicAdd(&q2[tid], sq[tid]);
  }
}

__global__ void k_finalize(const float* __restrict__ sum, const float* __restrict__ sq,
                           const float* __restrict__ g, const float* __restrict__ b,
                           float* __restrict__ a, float* __restrict__ c) {
  int j = threadIdx.x;
  const float inv = 1.0f / (float)N_NODES;
  float m = sum[j] * inv;
  float v = sq[j] * inv - m * m;
  float r = rsqrtf(v + 1e-5f);
  float aa = g[j] * r;
  a[j] = aa;
  c[j] = fmaf(-m, aa, b[j]);
}

// ---------------- pool: batch sorted -> one wave per graph, zero atomics ----
__global__ void __launch_bounds__(256)
k_pool(const float* __restrict__ z2, const float* __restrict__ a2,
       const float* __restrict__ c2, const int* __restrict__ batch,
       float* __restrict__ out) {
  int g = blockIdx.x * 4 + (threadIdx.x >> 6);
  int d = threadIdx.x & 63;
  int a = 0, b = N_NODES;
  while (a < b) { int m = (a + b) >> 1; if (batch[m] < g) a = m + 1; else b = m; }
  const int lo = a;
  b = N_NODES;
  while (a < b) { int m = (a + b) >> 1; if (batch[m] < g + 1) a = m + 1; else b = m; }
  const int hi = a;
  float s0 = 0.f, s1 = 0.f, s2 = 0.f, s3 = 0.f;
  int n = lo;
  for (; n + 4 <= hi; n += 4) {
    s0 += z2[(size_t)(n + 0) * 64 + d];
    s1 += z2[(size_t)(n + 1) * 64 + d];
    s2 += z2[(size_t)(n + 2) * 64 + d];
    s3 += z2[(size_t)(n + 3) * 64 + d];
  }
  for (; n < hi; ++n) s0 += z2[(size_t)n * 64 + d];
  float S = (s0 + s1) + (s2 + s3);
  float cntf = (float)(hi - lo);
  out[g * 64 + d] = fmaf(S, a2[d], cntf * c2[d]) / (cntf + 1e-9f);
}

extern "C" void kernel_launch(void* const* d_in, const int* in_sizes, int n_in,
                              void* d_out, int out_size, void* d_ws, size_t ws_size,
                              hipStream_t stream) {
  const int* x = (const int*)d_in[0];
  const int* ea = (const int*)d_in[1];
  const int* ei = (const int*)d_in[2];
  const int* batch = (const int*)d_in[3];
  const float* atom_emb = (const float*)d_in[4];
  const float* bond_emb = (const float*)d_in[5];
  const float* W1 = (const float*)d_in[6];
  const float* g1 = (const float*)d_in[8];
  const float* be1 = (const float*)d_in[9];
  const float* W2 = (const float*)d_in[10];
  const float* b2 = (const float*)d_in[11];
  const float* eps = (const float*)d_in[12];
  const float* bn_g = (const float*)d_in[13];
  const float* bn_b = (const float*)d_in[14];

  float* w = (float*)d_ws;
  float* A = w;                                 // h0, then z2
  float* B = w + (size_t)N_NODES * 64;
  float* stats = B + (size_t)N_NODES * 64;      // 4x(cs|M) = 16640
  float* s2 = stats + 16640;
  float* q2 = stats + 16704;
  float* a1 = stats + 16768;
  float* c1p = stats + 16896;
  float* a2 = stats + 17024;
  float* c2 = stats + 17088;
  int* ptr = (int*)(stats + 17152);             // 100001
  int* deg = ptr + (N_NODES + 1);               // 100000
  unsigned int* csr = (unsigned int*)(deg + N_NODES);  // 1.6M
  int* bs = (int*)(csr + N_EDGES);              // 391

  const int NBLK = (N_NODES + 255) / 256;   // 391
  const int NTILE = (N_NODES + 63) / 64;    // 1563
  const int NPULL = N_NODES / 32;           // 3125 (exact)
  const int NZ = NBLK;                      // 391

  hipMemsetAsync(deg, 0, N_NODES * sizeof(int), stream);

  k_atom_embed<<<N_NODES / 4, 256, 0, stream>>>(x, atom_emb, A);

  // CSR build (once; reused across all 4 layers)
  k_hist<<<(N_EDGES + 255) / 256, 256, 0, stream>>>(ei, deg);
  k_scan1<<<NBLK, 256, 0, stream>>>(deg, bs);
  k_scan2<<<1, 512, 0, stream>>>(bs, NBLK);
  k_scan3<<<NBLK, 256, 0, stream>>>(deg, bs, ptr);
  k_fill<<<(N_EDGES + 255) / 256, 256, 0, stream>>>(ei, ea, deg, csr);

  for (int l = 0; l < NL; ++l) {
    k_pull<<<NPULL, 256, 0, stream>>>(
        A, csr, ptr, bond_emb + (size_t)l * 1536, a2, c2, eps + l,
        (l > 0) ? 1 : 0, B, stats);
    k_zstats<<<NZ, 256, 0, stream>>>(B, stats);
    k_fin1<<<1, 128, 0, stream>>>(stats, W1 + (size_t)l * 8192,
                                  g1 + l * 128, be1 + l * 128, a1, c1p);
    k_mm2<<<NTILE, 256, 0, stream>>>(
        B, W1 + (size_t)l * 8192, a1, c1p, W2 + (size_t)l * 8192, b2 + l * 64,
        A, s2, q2);
    k_finalize<<<1, 64, 0, stream>>>(s2, q2, bn_g + l * 64, bn_b + l * 64, a2, c2);
  }
  k_pool<<<NG / 4, 256, 0, stream>>>(A, a2, c2, batch, (float*)d_out);
}

// Round 11
// 1253.366 us; speedup vs baseline: 1.3961x; 1.0222x over previous
//
#include <hip/hip_runtime.h>
#include <hip/hip_fp16.h>

#define N_NODES 100000
#define N_EDGES 1600000
#define NL 4
#define NG 1024
#define ZS 68    // LDS z-tile stride (64+4)
#define Z1S 132  // z1l row stride (128+4)

// ---------------------------------------------------------------------------
// ws layout (floats):
//   A      @ 0          : N*64 fp32  -- ALIASED: fp16 mirror A16 (N*64 halves)
//                         lives in the same bytes. atom_embed + mm2(l<3) write
//                         A16 only (pull gathers fp16, half the line traffic);
//                         mm2(l=3) writes fp32 A over the then-dead A16; pool
//                         reads fp32 A.
//   B      @ 6.4M       : N*64   z (pull out, zstats/mm2 in), fp32
//   stats  @ 12.8M      : 17152  [4 x (cs 64 | M 4096) | s2 | q2 | a1 | c1p | a2 | c2]
//   ints   @ ...        : ptr[100001] deg/cursor[100000] csr[1.6M] bs[391]
// ---------------------------------------------------------------------------

__global__ void k_atom_embed(const int* __restrict__ x, const float* __restrict__ emb,
                             __half* __restrict__ h16) {
  int n = blockIdx.x * 4 + (threadIdx.x >> 6);
  int d = threadIdx.x & 63;
  const int* xr = x + n * 9;
  float acc = 0.f;
#pragma unroll
  for (int c = 0; c < 9; ++c) acc += emb[(c * 100 + xr[c]) * 64 + d];
  h16[(size_t)n * 64 + d] = __float2half(acc);
}

// ---------------- CSR build (once per call) --------------------------------
__global__ void k_hist(const int* __restrict__ ei, int* __restrict__ deg) {
  int e = blockIdx.x * 256 + threadIdx.x;
  if (e < N_EDGES) atomicAdd(&deg[ei[e]], 1);
}

__global__ void k_scan1(const int* __restrict__ deg, int* __restrict__ bs) {
  __shared__ int s[256];
  int g = blockIdx.x * 256 + threadIdx.x;
  int v = (g < N_NODES) ? deg[g] : 0;
  s[threadIdx.x] = v;
  __syncthreads();
  for (int o = 128; o > 0; o >>= 1) {
    if (threadIdx.x < o) s[threadIdx.x] += s[threadIdx.x + o];
    __syncthreads();
  }
  if (threadIdx.x == 0) bs[blockIdx.x] = s[0];
}

__global__ void k_scan2(int* __restrict__ bs, int nblk) {
  __shared__ int s[512];
  int tid = threadIdx.x;
  int v = (tid < nblk) ? bs[tid] : 0;
  s[tid] = v;
  __syncthreads();
  for (int o = 1; o < 512; o <<= 1) {
    int t = (tid >= o) ? s[tid - o] : 0;
    __syncthreads();
    s[tid] += t;
    __syncthreads();
  }
  if (tid < nblk) bs[tid] = s[tid] - v;  // exclusive
}

__global__ void k_scan3(int* __restrict__ deg, const int* __restrict__ bs,
                        int* __restrict__ ptr) {
  __shared__ int s[256];
  int tid = threadIdx.x;
  int g = blockIdx.x * 256 + tid;
  int v = (g < N_NODES) ? deg[g] : 0;
  s[tid] = v;
  __syncthreads();
  for (int o = 1; o < 256; o <<= 1) {
    int t = (tid >= o) ? s[tid - o] : 0;
    __syncthreads();
    s[tid] += t;
    __syncthreads();
  }
  if (g < N_NODES) {
    int val = bs[blockIdx.x] + s[tid] - v;
    ptr[g] = val;
    deg[g] = val;  // reuse deg as fill cursor
  }
  if (g == 0) ptr[N_NODES] = N_EDGES;
}

__global__ void k_fill(const int* __restrict__ ei, const int* __restrict__ ea,
                       int* __restrict__ cur, unsigned int* __restrict__ csr) {
  int e = blockIdx.x * 256 + threadIdx.x;
  if (e >= N_EDGES) return;
  int s = ei[e];
  unsigned int dst = (unsigned int)ei[N_EDGES + e];
  unsigned int b = (unsigned int)(ea[e * 3] | (ea[e * 3 + 1] << 3) | (ea[e * 3 + 2] << 6));
  int pos = atomicAdd(&cur[s], 1);
  csr[pos] = dst | (b << 17);
}

// ---------------- pull-mode aggregation (fp16 gather source) ----------------
// wave = one node's 64 dims; csr chunk coalesced + shfl broadcast; 8-deep
// unrolled gathers. Source rows are fp16 (128B = 2 lines vs 4 for fp32):
// halves the per-gather line traffic that bounds this latency-limited kernel.
__global__ void __launch_bounds__(256)
k_pull(const __half* __restrict__ src, const unsigned int* __restrict__ csr,
       const int* __restrict__ ptr, const float* __restrict__ bond,
       const float* __restrict__ aprev, const float* __restrict__ cprev,
       const float* __restrict__ epsp, int reluf,
       float* __restrict__ z, float* __restrict__ stats0) {
  __shared__ float sb[1536];
  for (int i = threadIdx.x; i < 1536; i += 256) sb[i] = bond[i];
  if (blockIdx.x == 0)
    for (int i = threadIdx.x; i < 16768; i += 256) stats0[i] = 0.f;
  __syncthreads();
  const int wave = threadIdx.x >> 6, d = threadIdx.x & 63;
  const float ep1 = 1.0f + epsp[0];
  const float aA = reluf ? aprev[d] : 1.0f;
  const float cC = reluf ? cprev[d] : 0.0f;
  const int n0 = blockIdx.x * 32 + wave * 8;
#pragma unroll
  for (int ii = 0; ii < 8; ++ii) {
    int n = n0 + ii;
    int p0 = ptr[n], p1 = ptr[n + 1];
    float own = __half2float(src[(size_t)n * 64 + d]);
    if (reluf) own = fmaxf(fmaf(own, aA, cC), 0.f);
    float acc = ep1 * own;
    for (int base = p0; base < p1; base += 64) {
      int cnt = min(64, p1 - base);
      unsigned int mypk = (d < cnt) ? csr[base + d] : 0u;
      int i = 0;
      for (; i + 8 <= cnt; i += 8) {
        unsigned int pk[8];
        float v[8];
#pragma unroll
        for (int u = 0; u < 8; ++u) pk[u] = __shfl(mypk, i + u);
#pragma unroll
        for (int u = 0; u < 8; ++u)
          v[u] = __half2float(src[(size_t)(pk[u] & 0x1FFFFu) * 64 + d]);
#pragma unroll
        for (int u = 0; u < 8; ++u) {
          if (reluf) v[u] = fmaxf(fmaf(v[u], aA, cC), 0.f);
          unsigned int b = pk[u] >> 17;
          float ef = sb[(b & 7) * 64 + d] + sb[(((b >> 3) & 7) + 8) * 64 + d] +
                     sb[((b >> 6) + 16) * 64 + d];
          acc += fmaxf(v[u] + ef, 0.f);
        }
      }
      for (; i < cnt; ++i) {
        unsigned int pk = __shfl(mypk, i);
        float v = __half2float(src[(size_t)(pk & 0x1FFFFu) * 64 + d]);
        if (reluf) v = fmaxf(fmaf(v, aA, cC), 0.f);
        unsigned int b = pk >> 17;
        float ef = sb[(b & 7) * 64 + d] + sb[(((b >> 3) & 7) + 8) * 64 + d] +
                   sb[((b >> 6) + 16) * 64 + d];
        acc += fmaxf(v + ef, 0.f);
      }
    }
    z[(size_t)n * 64 + d] = acc;
  }
}

// ---------------- BN1 moments: colsum(z), M = z^T z -------------------------
__global__ void __launch_bounds__(256)
k_zstats(const float* __restrict__ z, float* __restrict__ stats) {
  __shared__ __align__(16) float zl[64 * ZS];
  __shared__ float red[256];
  const int tid = threadIdx.x;
  const int wave = tid >> 6, d = tid & 63;
  const int ar = (tid >> 4) * 4, bc = (tid & 15) * 4;
  float accS = 0.f;
  float m00 = 0.f, m01 = 0.f, m02 = 0.f, m03 = 0.f;
  float m10 = 0.f, m11 = 0.f, m12 = 0.f, m13 = 0.f;
  float m20 = 0.f, m21 = 0.f, m22 = 0.f, m23 = 0.f;
  float m30 = 0.f, m31 = 0.f, m32 = 0.f, m33 = 0.f;
  for (int t = 0; t < 4; ++t) {
    const int nb = (blockIdx.x * 4 + t) * 64;
    const int nlim = N_NODES - nb;
    __syncthreads();
    for (int i = tid; i < 1024; i += 256) {
      int n = i >> 4, k4 = (i & 15) << 2;
      float4 v = make_float4(0.f, 0.f, 0.f, 0.f);
      if (n < nlim) v = *(const float4*)&z[(size_t)(nb + n) * 64 + k4];
      *(float4*)&zl[n * ZS + k4] = v;
    }
    __syncthreads();
#pragma unroll
    for (int ii = 0; ii < 16; ++ii) accS += zl[(wave * 16 + ii) * ZS + d];
#pragma unroll 4
    for (int n = 0; n < 64; ++n) {
      const float4 a = *(const float4*)&zl[n * ZS + ar];
      const float4 b = *(const float4*)&zl[n * ZS + bc];
      m00 = fmaf(a.x, b.x, m00); m01 = fmaf(a.x, b.y, m01); m02 = fmaf(a.x, b.z, m02); m03 = fmaf(a.x, b.w, m03);
      m10 = fmaf(a.y, b.x, m10); m11 = fmaf(a.y, b.y, m11); m12 = fmaf(a.y, b.z, m12); m13 = fmaf(a.y, b.w, m13);
      m20 = fmaf(a.z, b.x, m20); m21 = fmaf(a.z, b.y, m21); m22 = fmaf(a.z, b.z, m22); m23 = fmaf(a.z, b.w, m23);
      m30 = fmaf(a.w, b.x, m30); m31 = fmaf(a.w, b.y, m31); m32 = fmaf(a.w, b.z, m32); m33 = fmaf(a.w, b.w, m33);
    }
  }
  float* copy = stats + (blockIdx.x & 3) * 4160;  // [cs 64 | M 4096]
  red[tid] = accS;
  __syncthreads();
  if (tid < 64)
    atomicAdd(&copy[tid], red[tid] + red[tid + 64] + red[tid + 128] + red[tid + 192]);
  float* M = copy + 64;
  atomicAdd(&M[(ar + 0) * 64 + bc + 0], m00); atomicAdd(&M[(ar + 0) * 64 + bc + 1], m01);
  atomicAdd(&M[(ar + 0) * 64 + bc + 2], m02); atomicAdd(&M[(ar + 0) * 64 + bc + 3], m03);
  atomicAdd(&M[(ar + 1) * 64 + bc + 0], m10); atomicAdd(&M[(ar + 1) * 64 + bc + 1], m11);
  atomicAdd(&M[(ar + 1) * 64 + bc + 2], m12); atomicAdd(&M[(ar + 1) * 64 + bc + 3], m13);
  atomicAdd(&M[(ar + 2) * 64 + bc + 0], m20); atomicAdd(&M[(ar + 2) * 64 + bc + 1], m21);
  atomicAdd(&M[(ar + 2) * 64 + bc + 2], m22); atomicAdd(&M[(ar + 2) * 64 + bc + 3], m23);
  atomicAdd(&M[(ar + 3) * 64 + bc + 0], m30); atomicAdd(&M[(ar + 3) * 64 + bc + 1], m31);
  atomicAdd(&M[(ar + 3) * 64 + bc + 2], m32); atomicAdd(&M[(ar + 3) * 64 + bc + 3], m33);
}

// BN1 params from moments (sums the 4 replicated copies)
__global__ void __launch_bounds__(128, 1)
k_fin1(const float* __restrict__ stats,
       const float* __restrict__ W1, const float* __restrict__ g1,
       const float* __restrict__ be1,
       float* __restrict__ a1, float* __restrict__ c1p) {
  __shared__ float Ml[4096];
  __shared__ float csl[64];
  int j = threadIdx.x;
  for (int i = j; i < 4096; i += 128)
    Ml[i] = stats[64 + i] + stats[4160 + 64 + i] + stats[8320 + 64 + i] + stats[12480 + 64 + i];
  if (j < 64) csl[j] = stats[j] + stats[4160 + j] + stats[8320 + j] + stats[12480 + j];
  __syncthreads();
  float wcol[64];
#pragma unroll
  for (int k = 0; k < 64; ++k) wcol[k] = W1[k * 128 + j];
  float m0 = 0.f;
#pragma unroll
  for (int k = 0; k < 64; ++k) m0 = fmaf(csl[k], wcol[k], m0);
  m0 *= (1.0f / (float)N_NODES);
  float q = 0.f;
  for (int ka = 0; ka < 64; ++ka) {
    const float4* mr = (const float4*)&Ml[ka * 64];
    float t = 0.f;
#pragma unroll
    for (int kb = 0; kb < 16; ++kb) {
      float4 m = mr[kb];
      t = fmaf(m.x, wcol[kb * 4 + 0], t);
      t = fmaf(m.y, wcol[kb * 4 + 1], t);
      t = fmaf(m.z, wcol[kb * 4 + 2], t);
      t = fmaf(m.w, wcol[kb * 4 + 3], t);
    }
    q = fmaf(wcol[ka], t, q);
  }
  float var = q * (1.0f / (float)N_NODES) - m0 * m0;
  float r = rsqrtf(var + 1e-5f);
  float A = g1[j] * r;
  a1[j] = A;
  c1p[j] = fmaf(-m0, A, be1[j]);
}

// fused MLP: z@W1 -> bn1 affine+relu -> z1l (LDS) -> @W2 -> z2 + stats2
// 49.5KB LDS (z1l overlays phase-A head; W2 in two 16KB halves) -> 3 blocks/CU.
// tofp16: layers 0-2 write the fp16 mirror only (half the write bytes); layer 3
// writes fp32 (for pool). Stats always computed from fp32 accumulators.
__global__ void __launch_bounds__(256, 3)
k_mm2(const float* __restrict__ z, const float* __restrict__ W1g,
      const float* __restrict__ a1, const float* __restrict__ c1p,
      const float* __restrict__ W2g, const float* __restrict__ b2,
      float* __restrict__ zout, __half* __restrict__ zout16, int tofp16,
      float* __restrict__ s2, float* __restrict__ q2) {
  __shared__ __align__(16) float sm[12672];
  float* zl = sm;            // [64][68]  phase A          (0..4352)
  float* w1l = sm + 4352;    // [64][128] phase A          (4352..12544)
  float* z1l = sm;           // [64][132] phase B, overlays (0..8448)
  float* w2l = sm + 8448;    // [64][64] half of W2        (8448..12544)
  float* ss = sm + 12544;
  float* sq = sm + 12608;
  int tid = threadIdx.x;
  int nb = blockIdx.x * 64;
  int nlim = N_NODES - nb;
  if (tid < 128) sm[12544 + tid] = 0.f;
  for (int i = tid; i < 1024; i += 256) {
    int n = i >> 4, k4 = (i & 15) << 2;
    float4 v = make_float4(0.f, 0.f, 0.f, 0.f);
    if (n < nlim) v = *(const float4*)&z[(size_t)(nb + n) * 64 + k4];
    *(float4*)&zl[n * ZS + k4] = v;
  }
  for (int i = tid; i < 2048; i += 256)
    *(float4*)&w1l[i * 4] = *(const float4*)&W1g[i * 4];
  __syncthreads();

  const int jg = tid & 15, ng = tid >> 4;
  const int n0 = ng * 4;
  float acc[4][8];
#pragma unroll
  for (int i = 0; i < 4; ++i)
#pragma unroll
    for (int c = 0; c < 8; ++c) acc[i][c] = 0.f;
#pragma unroll 2
  for (int k4 = 0; k4 < 16; ++k4) {
    float4 za[4];
#pragma unroll
    for (int i = 0; i < 4; ++i) za[i] = *(const float4*)&zl[(n0 + i) * ZS + k4 * 4];
#pragma unroll
    for (int kk = 0; kk < 4; ++kk) {
      const float4 w0 = *(const float4*)&w1l[(k4 * 4 + kk) * 128 + jg * 4];
      const float4 w1 = *(const float4*)&w1l[(k4 * 4 + kk) * 128 + 64 + jg * 4];
#pragma unroll
      for (int i = 0; i < 4; ++i) {
        const float zv = ((const float*)&za[i])[kk];
        acc[i][0] = fmaf(zv, w0.x, acc[i][0]);
        acc[i][1] = fmaf(zv, w0.y, acc[i][1]);
        acc[i][2] = fmaf(zv, w0.z, acc[i][2]);
        acc[i][3] = fmaf(zv, w0.w, acc[i][3]);
        acc[i][4] = fmaf(zv, w1.x, acc[i][4]);
        acc[i][5] = fmaf(zv, w1.y, acc[i][5]);
        acc[i][6] = fmaf(zv, w1.z, acc[i][6]);
        acc[i][7] = fmaf(zv, w1.w, acc[i][7]);
      }
    }
  }
  const float4 av0 = *(const float4*)&a1[jg * 4], av1 = *(const float4*)&a1[64 + jg * 4];
  const float4 cv0 = *(const float4*)&c1p[jg * 4], cv1 = *(const float4*)&c1p[64 + jg * 4];
  __syncthreads();  // zl/w1l reads done; accs in regs; safe to overlay
  const int sxor = ng & 7;
#pragma unroll
  for (int i = 0; i < 4; ++i) {
    float4 v0, v1;
    v0.x = fmaxf(fmaf(acc[i][0], av0.x, cv0.x), 0.f);
    v0.y = fmaxf(fmaf(acc[i][1], av0.y, cv0.y), 0.f);
    v0.z = fmaxf(fmaf(acc[i][2], av0.z, cv0.z), 0.f);
    v0.w = fmaxf(fmaf(acc[i][3], av0.w, cv0.w), 0.f);
    v1.x = fmaxf(fmaf(acc[i][4], av1.x, cv1.x), 0.f);
    v1.y = fmaxf(fmaf(acc[i][5], av1.y, cv1.y), 0.f);
    v1.z = fmaxf(fmaf(acc[i][6], av1.z, cv1.z), 0.f);
    v1.w = fmaxf(fmaf(acc[i][7], av1.w, cv1.w), 0.f);
    const int g0 = jg ^ sxor, g1i = 16 + (jg ^ sxor);
    *(float4*)&z1l[(n0 + i) * Z1S + g0 * 4] = v0;
    *(float4*)&z1l[(n0 + i) * Z1S + g1i * 4] = v1;
  }

  const int jb = (tid & 7) * 8, n0b = (tid >> 3) * 2;
  const float4 b20 = *(const float4*)&b2[jb], b21 = *(const float4*)&b2[jb + 4];
  float accB[2][8];
#pragma unroll
  for (int i = 0; i < 2; ++i) {
    accB[i][0] = b20.x; accB[i][1] = b20.y; accB[i][2] = b20.z; accB[i][3] = b20.w;
    accB[i][4] = b21.x; accB[i][5] = b21.y; accB[i][6] = b21.z; accB[i][7] = b21.w;
  }
#pragma unroll
  for (int kc = 0; kc < 2; ++kc) {
    __syncthreads();  // kc=0: z1l writes done; kc=1: w2l half0 reads done
    for (int i = tid; i < 1024; i += 256)
      *(float4*)&w2l[i * 4] = *(const float4*)&W2g[kc * 4096 + i * 4];
    __syncthreads();
#pragma unroll 2
    for (int k4 = 0; k4 < 16; ++k4) {
      const int kg = kc * 16 + k4;
      float4 zb[2];
#pragma unroll
      for (int i = 0; i < 2; ++i) {
        const int n = n0b + i;
        const int gs = kg ^ ((n >> 2) & 7);
        zb[i] = *(const float4*)&z1l[n * Z1S + gs * 4];
      }
#pragma unroll
      for (int kk = 0; kk < 4; ++kk) {
        const float4 w0 = *(const float4*)&w2l[(k4 * 4 + kk) * 64 + jb];
        const float4 w1 = *(const float4*)&w2l[(k4 * 4 + kk) * 64 + jb + 4];
#pragma unroll
        for (int i = 0; i < 2; ++i) {
          const float zv = ((const float*)&zb[i])[kk];
          accB[i][0] = fmaf(zv, w0.x, accB[i][0]);
          accB[i][1] = fmaf(zv, w0.y, accB[i][1]);
          accB[i][2] = fmaf(zv, w0.z, accB[i][2]);
          accB[i][3] = fmaf(zv, w0.w, accB[i][3]);
          accB[i][4] = fmaf(zv, w1.x, accB[i][4]);
          accB[i][5] = fmaf(zv, w1.y, accB[i][5]);
          accB[i][6] = fmaf(zv, w1.z, accB[i][6]);
          accB[i][7] = fmaf(zv, w1.w, accB[i][7]);
        }
      }
    }
  }
  float sj[8], qj[8];
#pragma unroll
  for (int c = 0; c < 8; ++c) { sj[c] = 0.f; qj[c] = 0.f; }
#pragma unroll
  for (int i = 0; i < 2; ++i) {
    const int n = n0b + i;
    if (n < nlim) {
      if (tofp16) {
        __half hbuf[8];
#pragma unroll
        for (int c = 0; c < 8; ++c) hbuf[c] = __float2half(accB[i][c]);
        *(uint4*)&zout16[(size_t)(nb + n) * 64 + jb] = *(uint4*)hbuf;
      } else {
        float4 o0, o1;
        o0.x = accB[i][0]; o0.y = accB[i][1]; o0.z = accB[i][2]; o0.w = accB[i][3];
        o1.x = accB[i][4]; o1.y = accB[i][5]; o1.z = accB[i][6]; o1.w = accB[i][7];
        *(float4*)&zout[(size_t)(nb + n) * 64 + jb] = o0;
        *(float4*)&zout[(size_t)(nb + n) * 64 + jb + 4] = o1;
      }
#pragma unroll
      for (int c = 0; c < 8; ++c) {
        sj[c] += accB[i][c];
        qj[c] = fmaf(accB[i][c], accB[i][c], qj[c]);
      }
    }
  }
#pragma unroll
  for (int c = 0; c < 8; ++c) {
    atomicAdd(&ss[jb + c], sj[c]);
    atomicAdd(&sq[jb + c], qj[c]);
  }
  __syncthreads();
  if (tid < 64) {
    atomicAdd(&s2[tid], ss[tid]);
    atomicAdd(&q2[tid], sq[tid]);
  }
}

__global__ void k_finalize(const float* __restrict__ sum, const float* __restrict__ sq,
                           const float* __restrict__ g, const float* __restrict__ b,
                           float* __restrict__ a, float* __restrict__ c) {
  int j = threadIdx.x;
  const float inv = 1.0f / (float)N_NODES;
  float m = sum[j] * inv;
  float v = sq[j] * inv - m * m;
  float r = rsqrtf(v + 1e-5f);
  float aa = g[j] * r;
  a[j] = aa;
  c[j] = fmaf(-m, aa, b[j]);
}

// ---------------- pool: batch sorted -> one wave per graph, zero atomics ----
__global__ void __launch_bounds__(256)
k_pool(const float* __restrict__ z2, const float* __restrict__ a2,
       const float* __restrict__ c2, const int* __restrict__ batch,
       float* __restrict__ out) {
  int g = blockIdx.x * 4 + (threadIdx.x >> 6);
  int d = threadIdx.x & 63;
  int a = 0, b = N_NODES;
  while (a < b) { int m = (a + b) >> 1; if (batch[m] < g) a = m + 1; else b = m; }
  const int lo = a;
  b = N_NODES;
  while (a < b) { int m = (a + b) >> 1; if (batch[m] < g + 1) a = m + 1; else b = m; }
  const int hi = a;
  float s0 = 0.f, s1 = 0.f, s2 = 0.f, s3 = 0.f;
  int n = lo;
  for (; n + 4 <= hi; n += 4) {
    s0 += z2[(size_t)(n + 0) * 64 + d];
    s1 += z2[(size_t)(n + 1) * 64 + d];
    s2 += z2[(size_t)(n + 2) * 64 + d];
    s3 += z2[(size_t)(n + 3) * 64 + d];
  }
  for (; n < hi; ++n) s0 += z2[(size_t)n * 64 + d];
  float S = (s0 + s1) + (s2 + s3);
  float cntf = (float)(hi - lo);
  out[g * 64 + d] = fmaf(S, a2[d], cntf * c2[d]) / (cntf + 1e-9f);
}

extern "C" void kernel_launch(void* const* d_in, const int* in_sizes, int n_in,
                              void* d_out, int out_size, void* d_ws, size_t ws_size,
                              hipStream_t stream) {
  const int* x = (const int*)d_in[0];
  const int* ea = (const int*)d_in[1];
  const int* ei = (const int*)d_in[2];
  const int* batch = (const int*)d_in[3];
  const float* atom_emb = (const float*)d_in[4];
  const float* bond_emb = (const float*)d_in[5];
  const float* W1 = (const float*)d_in[6];
  const float* g1 = (const float*)d_in[8];
  const float* be1 = (const float*)d_in[9];
  const float* W2 = (const float*)d_in[10];
  const float* b2 = (const float*)d_in[11];
  const float* eps = (const float*)d_in[12];
  const float* bn_g = (const float*)d_in[13];
  const float* bn_b = (const float*)d_in[14];

  float* w = (float*)d_ws;
  float* A = w;                                 // fp32 z2 (layer 3 only)
  __half* A16 = (__half*)w;                     // fp16 mirror, ALIASES A
  float* B = w + (size_t)N_NODES * 64;
  float* stats = B + (size_t)N_NODES * 64;      // 4x(cs|M) = 16640
  float* s2 = stats + 16640;
  float* q2 = stats + 16704;
  float* a1 = stats + 16768;
  float* c1p = stats + 16896;
  float* a2 = stats + 17024;
  float* c2 = stats + 17088;
  int* ptr = (int*)(stats + 17152);             // 100001
  int* deg = ptr + (N_NODES + 1);               // 100000
  unsigned int* csr = (unsigned int*)(deg + N_NODES);  // 1.6M
  int* bs = (int*)(csr + N_EDGES);              // 391

  const int NBLK = (N_NODES + 255) / 256;   // 391
  const int NTILE = (N_NODES + 63) / 64;    // 1563
  const int NPULL = N_NODES / 32;           // 3125 (exact)
  const int NZ = NBLK;                      // 391

  hipMemsetAsync(deg, 0, N_NODES * sizeof(int), stream);

  k_atom_embed<<<N_NODES / 4, 256, 0, stream>>>(x, atom_emb, A16);

  // CSR build (once; reused across all 4 layers)
  k_hist<<<(N_EDGES + 255) / 256, 256, 0, stream>>>(ei, deg);
  k_scan1<<<NBLK, 256, 0, stream>>>(deg, bs);
  k_scan2<<<1, 512, 0, stream>>>(bs, NBLK);
  k_scan3<<<NBLK, 256, 0, stream>>>(deg, bs, ptr);
  k_fill<<<(N_EDGES + 255) / 256, 256, 0, stream>>>(ei, ea, deg, csr);

  for (int l = 0; l < NL; ++l) {
    k_pull<<<NPULL, 256, 0, stream>>>(
        A16, csr, ptr, bond_emb + (size_t)l * 1536, a2, c2, eps + l,
        (l > 0) ? 1 : 0, B, stats);
    k_zstats<<<NZ, 256, 0, stream>>>(B, stats);
    k_fin1<<<1, 128, 0, stream>>>(stats, W1 + (size_t)l * 8192,
                                  g1 + l * 128, be1 + l * 128, a1, c1p);
    k_mm2<<<NTILE, 256, 0, stream>>>(
        B, W1 + (size_t)l * 8192, a1, c1p, W2 + (size_t)l * 8192, b2 + l * 64,
        A, A16, (l < NL - 1) ? 1 : 0, s2, q2);
    k_finalize<<<1, 64, 0, stream>>>(s2, q2, bn_g + l * 64, bn_b + l * 64, a2, c2);
  }
  k_pool<<<NG / 4, 256, 0, stream>>>(A, a2, c2, batch, (float*)d_out);
}

// Round 12
// 1229.155 us; speedup vs baseline: 1.4236x; 1.0197x over previous
//
#include <hip/hip_runtime.h>
#include <hip/hip_fp16.h>

#define N_NODES 100000
#define N_EDGES 1600000
#define NL 4
#define NG 1024
#define ZS 68    // LDS z-tile stride (64+4)
#define Z1S 132  // z1h row stride in HALVES (128+4)

// ---------------------------------------------------------------------------
// ws layout (floats):
//   A      @ 0          : N*64 fp32 -- ALIASED fp16 mirror A16; atom_embed +
//                         mm2(l<3) write fp16 (pull gathers fp16); mm2(l=3)
//                         writes fp32 for pool.
//   B      @ 6.4M       : N*64   z (pull out, zstats/mm2 in), fp32
//   stats  @ 12.8M      : 17152  [4 x (cs 64 | M 4096) | s2 | q2 | a1 | c1p | a2 | c2]
//   ints   @ ...        : ptr[100001] deg/cursor[100000] csr[1.6M] bs[391]
// ---------------------------------------------------------------------------

__global__ void k_atom_embed(const int* __restrict__ x, const float* __restrict__ emb,
                             __half* __restrict__ h16) {
  int n = blockIdx.x * 4 + (threadIdx.x >> 6);
  int d = threadIdx.x & 63;
  const int* xr = x + n * 9;
  float acc = 0.f;
#pragma unroll
  for (int c = 0; c < 9; ++c) acc += emb[(c * 100 + xr[c]) * 64 + d];
  h16[(size_t)n * 64 + d] = __float2half(acc);
}

// ---------------- CSR build (once per call) --------------------------------
__global__ void k_hist(const int* __restrict__ ei, int* __restrict__ deg) {
  int e = blockIdx.x * 256 + threadIdx.x;
  if (e < N_EDGES) atomicAdd(&deg[ei[e]], 1);
}

__global__ void k_scan1(const int* __restrict__ deg, int* __restrict__ bs) {
  __shared__ int s[256];
  int g = blockIdx.x * 256 + threadIdx.x;
  int v = (g < N_NODES) ? deg[g] : 0;
  s[threadIdx.x] = v;
  __syncthreads();
  for (int o = 128; o > 0; o >>= 1) {
    if (threadIdx.x < o) s[threadIdx.x] += s[threadIdx.x + o];
    __syncthreads();
  }
  if (threadIdx.x == 0) bs[blockIdx.x] = s[0];
}

__global__ void k_scan2(int* __restrict__ bs, int nblk) {
  __shared__ int s[512];
  int tid = threadIdx.x;
  int v = (tid < nblk) ? bs[tid] : 0;
  s[tid] = v;
  __syncthreads();
  for (int o = 1; o < 512; o <<= 1) {
    int t = (tid >= o) ? s[tid - o] : 0;
    __syncthreads();
    s[tid] += t;
    __syncthreads();
  }
  if (tid < nblk) bs[tid] = s[tid] - v;  // exclusive
}

__global__ void k_scan3(int* __restrict__ deg, const int* __restrict__ bs,
                        int* __restrict__ ptr) {
  __shared__ int s[256];
  int tid = threadIdx.x;
  int g = blockIdx.x * 256 + tid;
  int v = (g < N_NODES) ? deg[g] : 0;
  s[tid] = v;
  __syncthreads();
  for (int o = 1; o < 256; o <<= 1) {
    int t = (tid >= o) ? s[tid - o] : 0;
    __syncthreads();
    s[tid] += t;
    __syncthreads();
  }
  if (g < N_NODES) {
    int val = bs[blockIdx.x] + s[tid] - v;
    ptr[g] = val;
    deg[g] = val;  // reuse deg as fill cursor
  }
  if (g == 0) ptr[N_NODES] = N_EDGES;
}

__global__ void k_fill(const int* __restrict__ ei, const int* __restrict__ ea,
                       int* __restrict__ cur, unsigned int* __restrict__ csr) {
  int e = blockIdx.x * 256 + threadIdx.x;
  if (e >= N_EDGES) return;
  int s = ei[e];
  unsigned int dst = (unsigned int)ei[N_EDGES + e];
  unsigned int b = (unsigned int)(ea[e * 3] | (ea[e * 3 + 1] << 3) | (ea[e * 3 + 2] << 6));
  int pos = atomicAdd(&cur[s], 1);
  csr[pos] = dst | (b << 17);
}

// ---------------- pull-mode aggregation (fp16 gather source) ----------------
__global__ void __launch_bounds__(256)
k_pull(const __half* __restrict__ src, const unsigned int* __restrict__ csr,
       const int* __restrict__ ptr, const float* __restrict__ bond,
       const float* __restrict__ aprev, const float* __restrict__ cprev,
       const float* __restrict__ epsp, int reluf,
       float* __restrict__ z, float* __restrict__ stats0) {
  __shared__ float sb[1536];
  for (int i = threadIdx.x; i < 1536; i += 256) sb[i] = bond[i];
  if (blockIdx.x == 0)
    for (int i = threadIdx.x; i < 16768; i += 256) stats0[i] = 0.f;
  __syncthreads();
  const int wave = threadIdx.x >> 6, d = threadIdx.x & 63;
  const float ep1 = 1.0f + epsp[0];
  const float aA = reluf ? aprev[d] : 1.0f;
  const float cC = reluf ? cprev[d] : 0.0f;
  const int n0 = blockIdx.x * 32 + wave * 8;
#pragma unroll
  for (int ii = 0; ii < 8; ++ii) {
    int n = n0 + ii;
    int p0 = ptr[n], p1 = ptr[n + 1];
    float own = __half2float(src[(size_t)n * 64 + d]);
    if (reluf) own = fmaxf(fmaf(own, aA, cC), 0.f);
    float acc = ep1 * own;
    for (int base = p0; base < p1; base += 64) {
      int cnt = min(64, p1 - base);
      unsigned int mypk = (d < cnt) ? csr[base + d] : 0u;
      int i = 0;
      for (; i + 8 <= cnt; i += 8) {
        unsigned int pk[8];
        float v[8];
#pragma unroll
        for (int u = 0; u < 8; ++u) pk[u] = __shfl(mypk, i + u);
#pragma unroll
        for (int u = 0; u < 8; ++u)
          v[u] = __half2float(src[(size_t)(pk[u] & 0x1FFFFu) * 64 + d]);
#pragma unroll
        for (int u = 0; u < 8; ++u) {
          if (reluf) v[u] = fmaxf(fmaf(v[u], aA, cC), 0.f);
          unsigned int b = pk[u] >> 17;
          float ef = sb[(b & 7) * 64 + d] + sb[(((b >> 3) & 7) + 8) * 64 + d] +
                     sb[((b >> 6) + 16) * 64 + d];
          acc += fmaxf(v[u] + ef, 0.f);
        }
      }
      for (; i < cnt; ++i) {
        unsigned int pk = __shfl(mypk, i);
        float v = __half2float(src[(size_t)(pk & 0x1FFFFu) * 64 + d]);
        if (reluf) v = fmaxf(fmaf(v, aA, cC), 0.f);
        unsigned int b = pk >> 17;
        float ef = sb[(b & 7) * 64 + d] + sb[(((b >> 3) & 7) + 8) * 64 + d] +
                   sb[((b >> 6) + 16) * 64 + d];
        acc += fmaxf(v + ef, 0.f);
      }
    }
    z[(size_t)n * 64 + d] = acc;
  }
}

// ---------------- BN1 moments: colsum(z), M = z^T z -------------------------
// Double-buffered register prefetch: tile t+1's global loads issue BEFORE
// computing tile t (round-11: serialized load->sync->compute at 1.5 blocks/CU
// left HBM latency exposed; 45us vs ~15us compute floor).
__global__ void __launch_bounds__(256)
k_zstats(const float* __restrict__ z, float* __restrict__ stats) {
  __shared__ __align__(16) float zl[2][64 * ZS];
  __shared__ float red[256];
  const int tid = threadIdx.x;
  const int wave = tid >> 6, d = tid & 63;
  const int ar = (tid >> 4) * 4, bc = (tid & 15) * 4;
  const int nr = tid >> 4, kc4 = (tid & 15) << 2;  // this thread's load lanes
  float4 pf[4];

#define ZS_ISSUE(t)                                                        \
  {                                                                        \
    const int nb_ = (blockIdx.x * 4 + (t)) * 64;                           \
    const int nlim_ = N_NODES - nb_;                                       \
    _Pragma("unroll") for (int u = 0; u < 4; ++u) {                        \
      const int n_ = nr + u * 16;                                          \
      pf[u] = make_float4(0.f, 0.f, 0.f, 0.f);                             \
      if (n_ < nlim_) pf[u] = *(const float4*)&z[(size_t)(nb_ + n_) * 64 + kc4]; \
    }                                                                      \
  }
#define ZS_STORE(buf)                                                      \
  {                                                                        \
    _Pragma("unroll") for (int u = 0; u < 4; ++u)                          \
        *(float4*)&zl[buf][(nr + u * 16) * ZS + kc4] = pf[u];              \
  }

  ZS_ISSUE(0);
  ZS_STORE(0);
  __syncthreads();

  float accS = 0.f;
  float m00 = 0.f, m01 = 0.f, m02 = 0.f, m03 = 0.f;
  float m10 = 0.f, m11 = 0.f, m12 = 0.f, m13 = 0.f;
  float m20 = 0.f, m21 = 0.f, m22 = 0.f, m23 = 0.f;
  float m30 = 0.f, m31 = 0.f, m32 = 0.f, m33 = 0.f;
  for (int t = 0; t < 4; ++t) {
    const int cur = t & 1;
    if (t < 3) ZS_ISSUE(t + 1);  // loads in flight during compute below
#pragma unroll
    for (int ii = 0; ii < 16; ++ii) accS += zl[cur][(wave * 16 + ii) * ZS + d];
#pragma unroll 4
    for (int n = 0; n < 64; ++n) {
      const float4 a = *(const float4*)&zl[cur][n * ZS + ar];
      const float4 b = *(const float4*)&zl[cur][n * ZS + bc];
      m00 = fmaf(a.x, b.x, m00); m01 = fmaf(a.x, b.y, m01); m02 = fmaf(a.x, b.z, m02); m03 = fmaf(a.x, b.w, m03);
      m10 = fmaf(a.y, b.x, m10); m11 = fmaf(a.y, b.y, m11); m12 = fmaf(a.y, b.z, m12); m13 = fmaf(a.y, b.w, m13);
      m20 = fmaf(a.z, b.x, m20); m21 = fmaf(a.z, b.y, m21); m22 = fmaf(a.z, b.z, m22); m23 = fmaf(a.z, b.w, m23);
      m30 = fmaf(a.w, b.x, m30); m31 = fmaf(a.w, b.y, m31); m32 = fmaf(a.w, b.z, m32); m33 = fmaf(a.w, b.w, m33);
    }
    __syncthreads();
    if (t < 3) {
      ZS_STORE(cur ^ 1);
      __syncthreads();
    }
  }
  float* copy = stats + (blockIdx.x & 3) * 4160;  // [cs 64 | M 4096]
  red[tid] = accS;
  __syncthreads();
  if (tid < 64)
    atomicAdd(&copy[tid], red[tid] + red[tid + 64] + red[tid + 128] + red[tid + 192]);
  float* M = copy + 64;
  atomicAdd(&M[(ar + 0) * 64 + bc + 0], m00); atomicAdd(&M[(ar + 0) * 64 + bc + 1], m01);
  atomicAdd(&M[(ar + 0) * 64 + bc + 2], m02); atomicAdd(&M[(ar + 0) * 64 + bc + 3], m03);
  atomicAdd(&M[(ar + 1) * 64 + bc + 0], m10); atomicAdd(&M[(ar + 1) * 64 + bc + 1], m11);
  atomicAdd(&M[(ar + 1) * 64 + bc + 2], m12); atomicAdd(&M[(ar + 1) * 64 + bc + 3], m13);
  atomicAdd(&M[(ar + 2) * 64 + bc + 0], m20); atomicAdd(&M[(ar + 2) * 64 + bc + 1], m21);
  atomicAdd(&M[(ar + 2) * 64 + bc + 2], m22); atomicAdd(&M[(ar + 2) * 64 + bc + 3], m23);
  atomicAdd(&M[(ar + 3) * 64 + bc + 0], m30); atomicAdd(&M[(ar + 3) * 64 + bc + 1], m31);
  atomicAdd(&M[(ar + 3) * 64 + bc + 2], m32); atomicAdd(&M[(ar + 3) * 64 + bc + 3], m33);
#undef ZS_ISSUE
#undef ZS_STORE
}

// BN1 params from moments (sums the 4 replicated copies)
__global__ void __launch_bounds__(128, 1)
k_fin1(const float* __restrict__ stats,
       const float* __restrict__ W1, const float* __restrict__ g1,
       const float* __restrict__ be1,
       float* __restrict__ a1, float* __restrict__ c1p) {
  __shared__ float Ml[4096];
  __shared__ float csl[64];
  int j = threadIdx.x;
  for (int i = j; i < 4096; i += 128)
    Ml[i] = stats[64 + i] + stats[4160 + 64 + i] + stats[8320 + 64 + i] + stats[12480 + 64 + i];
  if (j < 64) csl[j] = stats[j] + stats[4160 + j] + stats[8320 + j] + stats[12480 + j];
  __syncthreads();
  float wcol[64];
#pragma unroll
  for (int k = 0; k < 64; ++k) wcol[k] = W1[k * 128 + j];
  float m0 = 0.f;
#pragma unroll
  for (int k = 0; k < 64; ++k) m0 = fmaf(csl[k], wcol[k], m0);
  m0 *= (1.0f / (float)N_NODES);
  float q = 0.f;
  for (int ka = 0; ka < 64; ++ka) {
    const float4* mr = (const float4*)&Ml[ka * 64];
    float t = 0.f;
#pragma unroll
    for (int kb = 0; kb < 16; ++kb) {
      float4 m = mr[kb];
      t = fmaf(m.x, wcol[kb * 4 + 0], t);
      t = fmaf(m.y, wcol[kb * 4 + 1], t);
      t = fmaf(m.z, wcol[kb * 4 + 2], t);
      t = fmaf(m.w, wcol[kb * 4 + 3], t);
    }
    q = fmaf(wcol[ka], t, q);
  }
  float var = q * (1.0f / (float)N_NODES) - m0 * m0;
  float r = rsqrtf(var + 1e-5f);
  float A = g1[j] * r;
  a1[j] = A;
  c1p[j] = fmaf(-m0, A, be1[j]);
}

// fused MLP: z@W1 (W1 in two 16KB halves) -> bn1 affine+relu -> z1 fp16 in LDS
// -> @W2 (two 16KB halves) -> z2 + stats2.  Peak LDS 34KB -> 4 blocks/CU
// (round-11: 49.5KB -> 3/CU). z1 fp16: post-BN O(1) values, fp32 accum kept.
__global__ void __launch_bounds__(256, 4)
k_mm2(const float* __restrict__ z, const float* __restrict__ W1g,
      const float* __restrict__ a1, const float* __restrict__ c1p,
      const float* __restrict__ W2g, const float* __restrict__ b2,
      float* __restrict__ zout, __half* __restrict__ zout16, int tofp16,
      float* __restrict__ s2, float* __restrict__ q2) {
  __shared__ __align__(16) float sm[8576];
  float* zl = sm;                  // [64][68]  floats 0..4352   (phase A)
  float* wl = sm + 4352;           // [64][64]  4352..8448 (W1 half / W2 half)
  __half* z1h = (__half*)sm;       // [64][132] halves 0..8448h = floats 0..4224 (phase B)
  float* ss = sm + 8448;
  float* sq = sm + 8512;
  int tid = threadIdx.x;
  int nb = blockIdx.x * 64;
  int nlim = N_NODES - nb;
  if (tid < 128) sm[8448 + tid] = 0.f;
  for (int i = tid; i < 1024; i += 256) {
    int n = i >> 4, k4 = (i & 15) << 2;
    float4 v = make_float4(0.f, 0.f, 0.f, 0.f);
    if (n < nlim) v = *(const float4*)&z[(size_t)(nb + n) * 64 + k4];
    *(float4*)&zl[n * ZS + k4] = v;
  }

  const int jg = tid & 15, ng = tid >> 4;
  const int n0 = ng * 4;
  float acc[4][8];
#pragma unroll
  for (int i = 0; i < 4; ++i)
#pragma unroll
    for (int c = 0; c < 8; ++c) acc[i][c] = 0.f;

#pragma unroll
  for (int jh = 0; jh < 2; ++jh) {
    __syncthreads();  // jh=0: zl/ss writes done; jh=1: half-0 wl reads done
    for (int i = tid; i < 1024; i += 256) {
      int k = i >> 4, j4 = (i & 15) << 2;
      *(float4*)&wl[k * 64 + j4] = *(const float4*)&W1g[k * 128 + jh * 64 + j4];
    }
    __syncthreads();
#pragma unroll 2
    for (int k4 = 0; k4 < 16; ++k4) {
      float4 za[4];
#pragma unroll
      for (int i = 0; i < 4; ++i) za[i] = *(const float4*)&zl[(n0 + i) * ZS + k4 * 4];
#pragma unroll
      for (int kk = 0; kk < 4; ++kk) {
        const float4 w0 = *(const float4*)&wl[(k4 * 4 + kk) * 64 + jg * 4];
#pragma unroll
        for (int i = 0; i < 4; ++i) {
          const float zv = ((const float*)&za[i])[kk];
          acc[i][jh * 4 + 0] = fmaf(zv, w0.x, acc[i][jh * 4 + 0]);
          acc[i][jh * 4 + 1] = fmaf(zv, w0.y, acc[i][jh * 4 + 1]);
          acc[i][jh * 4 + 2] = fmaf(zv, w0.z, acc[i][jh * 4 + 2]);
          acc[i][jh * 4 + 3] = fmaf(zv, w0.w, acc[i][jh * 4 + 3]);
        }
      }
    }
  }
  // acc[i][0..3] = cols 4jg..4jg+3 ; acc[i][4..7] = cols 64+4jg..64+4jg+3
  const float4 av0 = *(const float4*)&a1[jg * 4], av1 = *(const float4*)&a1[64 + jg * 4];
  const float4 cv0 = *(const float4*)&c1p[jg * 4], cv1 = *(const float4*)&c1p[64 + jg * 4];
  __syncthreads();  // all zl/wl reads done; accs in regs; safe to overlay z1h
  const int sxor = ng & 7;
#pragma unroll
  for (int i = 0; i < 4; ++i) {
    __half h0[4], h1[4];
    h0[0] = __float2half(fmaxf(fmaf(acc[i][0], av0.x, cv0.x), 0.f));
    h0[1] = __float2half(fmaxf(fmaf(acc[i][1], av0.y, cv0.y), 0.f));
    h0[2] = __float2half(fmaxf(fmaf(acc[i][2], av0.z, cv0.z), 0.f));
    h0[3] = __float2half(fmaxf(fmaf(acc[i][3], av0.w, cv0.w), 0.f));
    h1[0] = __float2half(fmaxf(fmaf(acc[i][4], av1.x, cv1.x), 0.f));
    h1[1] = __float2half(fmaxf(fmaf(acc[i][5], av1.y, cv1.y), 0.f));
    h1[2] = __float2half(fmaxf(fmaf(acc[i][6], av1.z, cv1.z), 0.f));
    h1[3] = __float2half(fmaxf(fmaf(acc[i][7], av1.w, cv1.w), 0.f));
    const int g0 = jg ^ sxor, g1i = 16 + (jg ^ sxor);
    *(uint2*)&z1h[(n0 + i) * Z1S + g0 * 4] = *(uint2*)h0;
    *(uint2*)&z1h[(n0 + i) * Z1S + g1i * 4] = *(uint2*)h1;
  }

  const int jb = (tid & 7) * 8, n0b = (tid >> 3) * 2;
  const float4 b20 = *(const float4*)&b2[jb], b21 = *(const float4*)&b2[jb + 4];
  float accB[2][8];
#pragma unroll
  for (int i = 0; i < 2; ++i) {
    accB[i][0] = b20.x; accB[i][1] = b20.y; accB[i][2] = b20.z; accB[i][3] = b20.w;
    accB[i][4] = b21.x; accB[i][5] = b21.y; accB[i][6] = b21.z; accB[i][7] = b21.w;
  }
#pragma unroll
  for (int kc = 0; kc < 2; ++kc) {
    __syncthreads();  // kc=0: z1h writes done; kc=1: wl half-0 reads done
    for (int i = tid; i < 1024; i += 256)
      *(float4*)&wl[i * 4] = *(const float4*)&W2g[kc * 4096 + i * 4];
    __syncthreads();
#pragma unroll 2
    for (int k4 = 0; k4 < 16; ++k4) {
      const int kg = kc * 16 + k4;
      float zb[2][4];
#pragma unroll
      for (int i = 0; i < 2; ++i) {
        const int n = n0b + i;
        const int gs = kg ^ ((n >> 2) & 7);
        uint2 raw = *(const uint2*)&z1h[n * Z1S + gs * 4];
        const __half* hp = (const __half*)&raw;
        zb[i][0] = __half2float(hp[0]);
        zb[i][1] = __half2float(hp[1]);
        zb[i][2] = __half2float(hp[2]);
        zb[i][3] = __half2float(hp[3]);
      }
#pragma unroll
      for (int kk = 0; kk < 4; ++kk) {
        const float4 w0 = *(const float4*)&wl[(k4 * 4 + kk) * 64 + jb];
        const float4 w1 = *(const float4*)&wl[(k4 * 4 + kk) * 64 + jb + 4];
#pragma unroll
        for (int i = 0; i < 2; ++i) {
          const float zv = zb[i][kk];
          accB[i][0] = fmaf(zv, w0.x, accB[i][0]);
          accB[i][1] = fmaf(zv, w0.y, accB[i][1]);
          accB[i][2] = fmaf(zv, w0.z, accB[i][2]);
          accB[i][3] = fmaf(zv, w0.w, accB[i][3]);
          accB[i][4] = fmaf(zv, w1.x, accB[i][4]);
          accB[i][5] = fmaf(zv, w1.y, accB[i][5]);
          accB[i][6] = fmaf(zv, w1.z, accB[i][6]);
          accB[i][7] = fmaf(zv, w1.w, accB[i][7]);
        }
      }
    }
  }
  float sj[8], qj[8];
#pragma unroll
  for (int c = 0; c < 8; ++c) { sj[c] = 0.f; qj[c] = 0.f; }
#pragma unroll
  for (int i = 0; i < 2; ++i) {
    const int n = n0b + i;
    if (n < nlim) {
      if (tofp16) {
        __half hbuf[8];
#pragma unroll
        for (int c = 0; c < 8; ++c) hbuf[c] = __float2half(accB[i][c]);
        *(uint4*)&zout16[(size_t)(nb + n) * 64 + jb] = *(uint4*)hbuf;
      } else {
        float4 o0, o1;
        o0.x = accB[i][0]; o0.y = accB[i][1]; o0.z = accB[i][2]; o0.w = accB[i][3];
        o1.x = accB[i][4]; o1.y = accB[i][5]; o1.z = accB[i][6]; o1.w = accB[i][7];
        *(float4*)&zout[(size_t)(nb + n) * 64 + jb] = o0;
        *(float4*)&zout[(size_t)(nb + n) * 64 + jb + 4] = o1;
      }
#pragma unroll
      for (int c = 0; c < 8; ++c) {
        sj[c] += accB[i][c];
        qj[c] = fmaf(accB[i][c], accB[i][c], qj[c]);
      }
    }
  }
#pragma unroll
  for (int c = 0; c < 8; ++c) {
    atomicAdd(&ss[jb + c], sj[c]);
    atomicAdd(&sq[jb + c], qj[c]);
  }
  __syncthreads();
  if (tid < 64) {
    atomicAdd(&s2[tid], ss[tid]);
    atomicAdd(&q2[tid], sq[tid]);
  }
}

__global__ void k_finalize(const float* __restrict__ sum, const float* __restrict__ sq,
                           const float* __restrict__ g, const float* __restrict__ b,
                           float* __restrict__ a, float* __restrict__ c) {
  int j = threadIdx.x;
  const float inv = 1.0f / (float)N_NODES;
  float m = sum[j] * inv;
  float v = sq[j] * inv - m * m;
  float r = rsqrtf(v + 1e-5f);
  float aa = g[j] * r;
  a[j] = aa;
  c[j] = fmaf(-m, aa, b[j]);
}

// ---------------- pool: batch sorted -> one wave per graph, zero atomics ----
__global__ void __launch_bounds__(256)
k_pool(const float* __restrict__ z2, const float* __restrict__ a2,
       const float* __restrict__ c2, const int* __restrict__ batch,
       float* __restrict__ out) {
  int g = blockIdx.x * 4 + (threadIdx.x >> 6);
  int d = threadIdx.x & 63;
  int a = 0, b = N_NODES;
  while (a < b) { int m = (a + b) >> 1; if (batch[m] < g) a = m + 1; else b = m; }
  const int lo = a;
  b = N_NODES;
  while (a < b) { int m = (a + b) >> 1; if (batch[m] < g + 1) a = m + 1; else b = m; }
  const int hi = a;
  float s0 = 0.f, s1 = 0.f, s2 = 0.f, s3 = 0.f;
  int n = lo;
  for (; n + 4 <= hi; n += 4) {
    s0 += z2[(size_t)(n + 0) * 64 + d];
    s1 += z2[(size_t)(n + 1) * 64 + d];
    s2 += z2[(size_t)(n + 2) * 64 + d];
    s3 += z2[(size_t)(n + 3) * 64 + d];
  }
  for (; n < hi; ++n) s0 += z2[(size_t)n * 64 + d];
  float S = (s0 + s1) + (s2 + s3);
  float cntf = (float)(hi - lo);
  out[g * 64 + d] = fmaf(S, a2[d], cntf * c2[d]) / (cntf + 1e-9f);
}

extern "C" void kernel_launch(void* const* d_in, const int* in_sizes, int n_in,
                              void* d_out, int out_size, void* d_ws, size_t ws_size,
                              hipStream_t stream) {
  const int* x = (const int*)d_in[0];
  const int* ea = (const int*)d_in[1];
  const int* ei = (const int*)d_in[2];
  const int* batch = (const int*)d_in[3];
  const float* atom_emb = (const float*)d_in[4];
  const float* bond_emb = (const float*)d_in[5];
  const float* W1 = (const float*)d_in[6];
  const float* g1 = (const float*)d_in[8];
  const float* be1 = (const float*)d_in[9];
  const float* W2 = (const float*)d_in[10];
  const float* b2 = (const float*)d_in[11];
  const float* eps = (const float*)d_in[12];
  const float* bn_g = (const float*)d_in[13];
  const float* bn_b = (const float*)d_in[14];

  float* w = (float*)d_ws;
  float* A = w;                                 // fp32 z2 (layer 3 only)
  __half* A16 = (__half*)w;                     // fp16 mirror, ALIASES A
  float* B = w + (size_t)N_NODES * 64;
  float* stats = B + (size_t)N_NODES * 64;      // 4x(cs|M) = 16640
  float* s2 = stats + 16640;
  float* q2 = stats + 16704;
  float* a1 = stats + 16768;
  float* c1p = stats + 16896;
  float* a2 = stats + 17024;
  float* c2 = stats + 17088;
  int* ptr = (int*)(stats + 17152);             // 100001
  int* deg = ptr + (N_NODES + 1);               // 100000
  unsigned int* csr = (unsigned int*)(deg + N_NODES);  // 1.6M
  int* bs = (int*)(csr + N_EDGES);              // 391

  const int NBLK = (N_NODES + 255) / 256;   // 391
  const int NTILE = (N_NODES + 63) / 64;    // 1563
  const int NPULL = N_NODES / 32;           // 3125 (exact)
  const int NZ = NBLK;                      // 391

  hipMemsetAsync(deg, 0, N_NODES * sizeof(int), stream);

  k_atom_embed<<<N_NODES / 4, 256, 0, stream>>>(x, atom_emb, A16);

  // CSR build (once; reused across all 4 layers)
  k_hist<<<(N_EDGES + 255) / 256, 256, 0, stream>>>(ei, deg);
  k_scan1<<<NBLK, 256, 0, stream>>>(deg, bs);
  k_scan2<<<1, 512, 0, stream>>>(bs, NBLK);
  k_scan3<<<NBLK, 256, 0, stream>>>(deg, bs, ptr);
  k_fill<<<(N_EDGES + 255) / 256, 256, 0, stream>>>(ei, ea, deg, csr);

  for (int l = 0; l < NL; ++l) {
    k_pull<<<NPULL, 256, 0, stream>>>(
        A16, csr, ptr, bond_emb + (size_t)l * 1536, a2, c2, eps + l,
        (l > 0) ? 1 : 0, B, stats);
    k_zstats<<<NZ, 256, 0, stream>>>(B, stats);
    k_fin1<<<1, 128, 0, stream>>>(stats, W1 + (size_t)l * 8192,
                                  g1 + l * 128, be1 + l * 128, a1, c1p);
    k_mm2<<<NTILE, 256, 0, stream>>>(
        B, W1 + (size_t)l * 8192, a1, c1p, W2 + (size_t)l * 8192, b2 + l * 64,
        A, A16, (l < NL - 1) ? 1 : 0, s2, q2);
    k_finalize<<<1, 64, 0, stream>>>(s2, q2, bn_g + l * 64, bn_b + l * 64, a2, c2);
  }
  k_pool<<<NG / 4, 256, 0, stream>>>(A, a2, c2, batch, (float*)d_out);
}

// Round 13
// 1159.067 us; speedup vs baseline: 1.5097x; 1.0605x over previous
//
#include <hip/hip_runtime.h>
#include <hip/hip_fp16.h>

#define N_NODES 100000
#define N_EDGES 1600000
#define NL 4
#define NG 1024
#define ZS 68    // zstats LDS fp32 tile stride

typedef _Float16 f16x8 __attribute__((ext_vector_type(8)));
typedef float f32x4 __attribute__((ext_vector_type(4)));

// ---------------------------------------------------------------------------
// ws layout (floats):
//   A      @ 0        : N*64 fp32 -- ALIASED fp16 mirror A16 (gather source /
//                       z2). mm2(l=3) writes fp32 for pool.
//   B      @ 6.4M     : N*64 slot; holds z16 (fp16) = pull out, zstats/mm2 in
//   stats  @ 12.8M    : [4 x (cs 64 | M 4096) | s2 64 | q2 64 | a1 128 |
//                        c1p 128 | a2 64 | c2 64 | w1t16 4096f | w2t16 4096f]
//   ints   @ ...      : ptr[100001] deg[100000] csr[1.6M] bs[391]
// ---------------------------------------------------------------------------

__global__ void k_atom_embed(const int* __restrict__ x, const float* __restrict__ emb,
                             __half* __restrict__ h16) {
  int n = blockIdx.x * 4 + (threadIdx.x >> 6);
  int d = threadIdx.x & 63;
  const int* xr = x + n * 9;
  float acc = 0.f;
#pragma unroll
  for (int c = 0; c < 9; ++c) acc += emb[(c * 100 + xr[c]) * 64 + d];
  h16[(size_t)n * 64 + d] = __float2half(acc);
}

// ---------------- CSR build (once per call) --------------------------------
__global__ void k_hist(const int* __restrict__ ei, int* __restrict__ deg) {
  int e = blockIdx.x * 256 + threadIdx.x;
  if (e < N_EDGES) atomicAdd(&deg[ei[e]], 1);
}

__global__ void k_scan1(const int* __restrict__ deg, int* __restrict__ bs) {
  __shared__ int s[256];
  int g = blockIdx.x * 256 + threadIdx.x;
  int v = (g < N_NODES) ? deg[g] : 0;
  s[threadIdx.x] = v;
  __syncthreads();
  for (int o = 128; o > 0; o >>= 1) {
    if (threadIdx.x < o) s[threadIdx.x] += s[threadIdx.x + o];
    __syncthreads();
  }
  if (threadIdx.x == 0) bs[blockIdx.x] = s[0];
}

__global__ void k_scan2(int* __restrict__ bs, int nblk) {
  __shared__ int s[512];
  int tid = threadIdx.x;
  int v = (tid < nblk) ? bs[tid] : 0;
  s[tid] = v;
  __syncthreads();
  for (int o = 1; o < 512; o <<= 1) {
    int t = (tid >= o) ? s[tid - o] : 0;
    __syncthreads();
    s[tid] += t;
    __syncthreads();
  }
  if (tid < nblk) bs[tid] = s[tid] - v;  // exclusive
}

__global__ void k_scan3(int* __restrict__ deg, const int* __restrict__ bs,
                        int* __restrict__ ptr) {
  __shared__ int s[256];
  int tid = threadIdx.x;
  int g = blockIdx.x * 256 + tid;
  int v = (g < N_NODES) ? deg[g] : 0;
  s[tid] = v;
  __syncthreads();
  for (int o = 1; o < 256; o <<= 1) {
    int t = (tid >= o) ? s[tid - o] : 0;
    __syncthreads();
    s[tid] += t;
    __syncthreads();
  }
  if (g < N_NODES) {
    int val = bs[blockIdx.x] + s[tid] - v;
    ptr[g] = val;
    deg[g] = val;  // reuse deg as fill cursor
  }
  if (g == 0) ptr[N_NODES] = N_EDGES;
}

__global__ void k_fill(const int* __restrict__ ei, const int* __restrict__ ea,
                       int* __restrict__ cur, unsigned int* __restrict__ csr) {
  int e = blockIdx.x * 256 + threadIdx.x;
  if (e >= N_EDGES) return;
  int s = ei[e];
  unsigned int dst = (unsigned int)ei[N_EDGES + e];
  unsigned int b = (unsigned int)(ea[e * 3] | (ea[e * 3 + 1] << 3) | (ea[e * 3 + 2] << 6));
  int pos = atomicAdd(&cur[s], 1);
  csr[pos] = dst | (b << 17);
}

// ---------------- pull-mode aggregation (fp16 in, fp16 out) -----------------
__global__ void __launch_bounds__(256)
k_pull(const __half* __restrict__ src, const unsigned int* __restrict__ csr,
       const int* __restrict__ ptr, const float* __restrict__ bond,
       const float* __restrict__ aprev, const float* __restrict__ cprev,
       const float* __restrict__ epsp, int reluf,
       __half* __restrict__ z, float* __restrict__ stats0) {
  __shared__ float sb[1536];
  for (int i = threadIdx.x; i < 1536; i += 256) sb[i] = bond[i];
  if (blockIdx.x == 0)
    for (int i = threadIdx.x; i < 16768; i += 256) stats0[i] = 0.f;
  __syncthreads();
  const int wave = threadIdx.x >> 6, d = threadIdx.x & 63;
  const float ep1 = 1.0f + epsp[0];
  const float aA = reluf ? aprev[d] : 1.0f;
  const float cC = reluf ? cprev[d] : 0.0f;
  const int n0 = blockIdx.x * 32 + wave * 8;
#pragma unroll
  for (int ii = 0; ii < 8; ++ii) {
    int n = n0 + ii;
    int p0 = ptr[n], p1 = ptr[n + 1];
    float own = __half2float(src[(size_t)n * 64 + d]);
    if (reluf) own = fmaxf(fmaf(own, aA, cC), 0.f);
    float acc = ep1 * own;
    for (int base = p0; base < p1; base += 64) {
      int cnt = min(64, p1 - base);
      unsigned int mypk = (d < cnt) ? csr[base + d] : 0u;
      int i = 0;
      for (; i + 8 <= cnt; i += 8) {
        unsigned int pk[8];
        float v[8];
#pragma unroll
        for (int u = 0; u < 8; ++u) pk[u] = __shfl(mypk, i + u);
#pragma unroll
        for (int u = 0; u < 8; ++u)
          v[u] = __half2float(src[(size_t)(pk[u] & 0x1FFFFu) * 64 + d]);
#pragma unroll
        for (int u = 0; u < 8; ++u) {
          if (reluf) v[u] = fmaxf(fmaf(v[u], aA, cC), 0.f);
          unsigned int b = pk[u] >> 17;
          float ef = sb[(b & 7) * 64 + d] + sb[(((b >> 3) & 7) + 8) * 64 + d] +
                     sb[((b >> 6) + 16) * 64 + d];
          acc += fmaxf(v[u] + ef, 0.f);
        }
      }
      for (; i < cnt; ++i) {
        unsigned int pk = __shfl(mypk, i);
        float v = __half2float(src[(size_t)(pk & 0x1FFFFu) * 64 + d]);
        if (reluf) v = fmaxf(fmaf(v, aA, cC), 0.f);
        unsigned int b = pk >> 17;
        float ef = sb[(b & 7) * 64 + d] + sb[(((b >> 3) & 7) + 8) * 64 + d] +
                   sb[((b >> 6) + 16) * 64 + d];
        acc += fmaxf(v + ef, 0.f);
      }
    }
    z[(size_t)n * 64 + d] = __float2half(acc);
  }
}

// ---------------- BN1 moments from z16: colsum, M = z^T z -------------------
__global__ void __launch_bounds__(256)
k_zstats(const __half* __restrict__ z, float* __restrict__ stats) {
  __shared__ __align__(16) float zl[2][64 * ZS];
  __shared__ float red[256];
  const int tid = threadIdx.x;
  const int wave = tid >> 6, d = tid & 63;
  const int ar = (tid >> 4) * 4, bc = (tid & 15) * 4;
  const int nr = tid >> 4, kc4 = (tid & 15) << 2;
  uint2 pf[4];

#define ZS_ISSUE(t)                                                           \
  {                                                                           \
    const int nb_ = (blockIdx.x * 4 + (t)) * 64;                              \
    const int nlim_ = N_NODES - nb_;                                          \
    _Pragma("unroll") for (int u = 0; u < 4; ++u) {                           \
      const int n_ = nr + u * 16;                                             \
      pf[u] = make_uint2(0u, 0u);                                             \
      if (n_ < nlim_) pf[u] = *(const uint2*)&z[(size_t)(nb_ + n_) * 64 + kc4]; \
    }                                                                         \
  }
#define ZS_STORE(buf)                                                         \
  {                                                                           \
    _Pragma("unroll") for (int u = 0; u < 4; ++u) {                           \
      const __half* hp_ = (const __half*)&pf[u];                              \
      float4 f_ = make_float4(__half2float(hp_[0]), __half2float(hp_[1]),     \
                              __half2float(hp_[2]), __half2float(hp_[3]));    \
      *(float4*)&zl[buf][(nr + u * 16) * ZS + kc4] = f_;                      \
    }                                                                         \
  }

  ZS_ISSUE(0);
  ZS_STORE(0);
  __syncthreads();

  float accS = 0.f;
  float m00 = 0.f, m01 = 0.f, m02 = 0.f, m03 = 0.f;
  float m10 = 0.f, m11 = 0.f, m12 = 0.f, m13 = 0.f;
  float m20 = 0.f, m21 = 0.f, m22 = 0.f, m23 = 0.f;
  float m30 = 0.f, m31 = 0.f, m32 = 0.f, m33 = 0.f;
  for (int t = 0; t < 4; ++t) {
    const int cur = t & 1;
    if (t < 3) ZS_ISSUE(t + 1);
#pragma unroll
    for (int ii = 0; ii < 16; ++ii) accS += zl[cur][(wave * 16 + ii) * ZS + d];
#pragma unroll 4
    for (int n = 0; n < 64; ++n) {
      const float4 a = *(const float4*)&zl[cur][n * ZS + ar];
      const float4 b = *(const float4*)&zl[cur][n * ZS + bc];
      m00 = fmaf(a.x, b.x, m00); m01 = fmaf(a.x, b.y, m01); m02 = fmaf(a.x, b.z, m02); m03 = fmaf(a.x, b.w, m03);
      m10 = fmaf(a.y, b.x, m10); m11 = fmaf(a.y, b.y, m11); m12 = fmaf(a.y, b.z, m12); m13 = fmaf(a.y, b.w, m13);
      m20 = fmaf(a.z, b.x, m20); m21 = fmaf(a.z, b.y, m21); m22 = fmaf(a.z, b.z, m22); m23 = fmaf(a.z, b.w, m23);
      m30 = fmaf(a.w, b.x, m30); m31 = fmaf(a.w, b.y, m31); m32 = fmaf(a.w, b.z, m32); m33 = fmaf(a.w, b.w, m33);
    }
    __syncthreads();
    if (t < 3) {
      ZS_STORE(cur ^ 1);
      __syncthreads();
    }
  }
  float* copy = stats + (blockIdx.x & 3) * 4160;  // [cs 64 | M 4096]
  red[tid] = accS;
  __syncthreads();
  if (tid < 64)
    atomicAdd(&copy[tid], red[tid] + red[tid + 64] + red[tid + 128] + red[tid + 192]);
  float* M = copy + 64;
  atomicAdd(&M[(ar + 0) * 64 + bc + 0], m00); atomicAdd(&M[(ar + 0) * 64 + bc + 1], m01);
  atomicAdd(&M[(ar + 0) * 64 + bc + 2], m02); atomicAdd(&M[(ar + 0) * 64 + bc + 3], m03);
  atomicAdd(&M[(ar + 1) * 64 + bc + 0], m10); atomicAdd(&M[(ar + 1) * 64 + bc + 1], m11);
  atomicAdd(&M[(ar + 1) * 64 + bc + 2], m12); atomicAdd(&M[(ar + 1) * 64 + bc + 3], m13);
  atomicAdd(&M[(ar + 2) * 64 + bc + 0], m20); atomicAdd(&M[(ar + 2) * 64 + bc + 1], m21);
  atomicAdd(&M[(ar + 2) * 64 + bc + 2], m22); atomicAdd(&M[(ar + 2) * 64 + bc + 3], m23);
  atomicAdd(&M[(ar + 3) * 64 + bc + 0], m30); atomicAdd(&M[(ar + 3) * 64 + bc + 1], m31);
  atomicAdd(&M[(ar + 3) * 64 + bc + 2], m32); atomicAdd(&M[(ar + 3) * 64 + bc + 3], m33);
#undef ZS_ISSUE
#undef ZS_STORE
}

// BN1 params + fp16 transposed weight tables (w1t[j][k], w2t[j][k])
__global__ void __launch_bounds__(128, 1)
k_fin1(const float* __restrict__ stats,
       const float* __restrict__ W1, const float* __restrict__ W2,
       const float* __restrict__ g1, const float* __restrict__ be1,
       float* __restrict__ a1, float* __restrict__ c1p,
       __half* __restrict__ w1t16, __half* __restrict__ w2t16) {
  __shared__ float Ml[4096];
  __shared__ float csl[64];
  int j = threadIdx.x;
  for (int i = j; i < 4096; i += 128)
    Ml[i] = stats[64 + i] + stats[4160 + 64 + i] + stats[8320 + 64 + i] + stats[12480 + 64 + i];
  if (j < 64) csl[j] = stats[j] + stats[4160 + j] + stats[8320 + j] + stats[12480 + j];
  __syncthreads();
  float wcol[64];
#pragma unroll
  for (int k = 0; k < 64; ++k) wcol[k] = W1[k * 128 + j];
#pragma unroll
  for (int k = 0; k < 64; ++k) w1t16[j * 64 + k] = __float2half(wcol[k]);
  for (int i = j; i < 8192; i += 128) {
    int k = i >> 6, jj = i & 63;
    w2t16[jj * 128 + k] = __float2half(W2[i]);
  }
  float m0 = 0.f;
#pragma unroll
  for (int k = 0; k < 64; ++k) m0 = fmaf(csl[k], wcol[k], m0);
  m0 *= (1.0f / (float)N_NODES);
  float q = 0.f;
  for (int ka = 0; ka < 64; ++ka) {
    const float4* mr = (const float4*)&Ml[ka * 64];
    float t = 0.f;
#pragma unroll
    for (int kb = 0; kb < 16; ++kb) {
      float4 m = mr[kb];
      t = fmaf(m.x, wcol[kb * 4 + 0], t);
      t = fmaf(m.y, wcol[kb * 4 + 1], t);
      t = fmaf(m.z, wcol[kb * 4 + 2], t);
      t = fmaf(m.w, wcol[kb * 4 + 3], t);
    }
    q = fmaf(wcol[ka], t, q);
  }
  float var = q * (1.0f / (float)N_NODES) - m0 * m0;
  float r = rsqrtf(var + 1e-5f);
  float A = g1[j] * r;
  a1[j] = A;
  c1p[j] = fmaf(-m0, A, be1[j]);
}

// ---------------- fused MLP on MFMA (v_mfma_f32_16x16x32_f16) ---------------
// 64 nodes/block, 4 waves. Phase A: z16@W1t -> bn1 affine+relu -> z1 fp16 LDS.
// Phase B: z1@W2t (two K-halves) -> z2 + stats. Fragment layouts per guide:
// A/B: row(=out row / out col) = lane&15, in-lane K contiguous-8 at 8*(lane>>4);
// C/D: col = lane&15, row = (lane>>4)*4 + reg  [learn_hip m89/m92-verified].
__global__ void __launch_bounds__(256)
k_mm2(const __half* __restrict__ z16, const __half* __restrict__ w1t,
      const float* __restrict__ a1, const float* __restrict__ c1p,
      const __half* __restrict__ w2t, const float* __restrict__ b2,
      float* __restrict__ zout, __half* __restrict__ zout16, int tofp16,
      float* __restrict__ s2, float* __restrict__ q2) {
  __shared__ __align__(16) float sm[7040];           // 28.2 KB
  __half* z16l = (__half*)sm;                        // [64][72]  bytes [0,9216)
  __half* w1tl = (__half*)(sm + 2304);               // [128][72] [9216,27648)
  __half* z1h = (__half*)sm;                         // [64][136] [0,17408) phase B
  __half* w2tl = (__half*)(sm + 4352);               // [64][72]  [17408,26624)
  float* ss = sm + 6912;
  float* sq = sm + 6976;
  const int tid = threadIdx.x;
  const int nb = blockIdx.x * 64;
  const int nlim = N_NODES - nb;
  const int wv = tid >> 6, l = tid & 63;
  const int lrow = l & 15, lk = l >> 4;
  if (tid < 128) sm[6912 + tid] = 0.f;
  {  // stage z16 tile (zero-fill tail rows)
    int row = tid >> 2, seg = (tid & 3) * 16;
#pragma unroll
    for (int c = 0; c < 4; ++c) {
      uint2 v = make_uint2(0u, 0u);
      if (row < nlim) v = *(const uint2*)&z16[(size_t)(nb + row) * 64 + seg + c * 4];
      *(uint2*)&z16l[row * 72 + seg + c * 4] = v;
    }
  }
  {  // stage W1t
    int row = tid >> 1, seg = (tid & 1) * 32;
#pragma unroll
    for (int c = 0; c < 8; ++c)
      *(uint2*)&w1tl[row * 72 + seg + c * 4] = *(const uint2*)&w1t[row * 64 + seg + c * 4];
  }
  __syncthreads();

  f32x4 acc[8];
#pragma unroll
  for (int jt = 0; jt < 8; ++jt) {
    f32x4 zr = {0.f, 0.f, 0.f, 0.f};
    acc[jt] = zr;
  }
  const f16x8 af0 = *(const f16x8*)&z16l[(16 * wv + lrow) * 72 + lk * 8];
  const f16x8 af1 = *(const f16x8*)&z16l[(16 * wv + lrow) * 72 + 32 + lk * 8];
#pragma unroll
  for (int jt = 0; jt < 8; ++jt) {
    const f16x8 b0 = *(const f16x8*)&w1tl[(lrow + 16 * jt) * 72 + lk * 8];
    const f16x8 b1 = *(const f16x8*)&w1tl[(lrow + 16 * jt) * 72 + 32 + lk * 8];
    acc[jt] = __builtin_amdgcn_mfma_f32_16x16x32_f16(af0, b0, acc[jt], 0, 0, 0);
    acc[jt] = __builtin_amdgcn_mfma_f32_16x16x32_f16(af1, b1, acc[jt], 0, 0, 0);
  }
  __syncthreads();  // z16l / w1tl reads complete; safe to overlay

  // bn1 affine + relu -> z1h (fp16); stage W2t half 0
#pragma unroll
  for (int jt = 0; jt < 8; ++jt) {
    const int col = lrow + 16 * jt;
    const float a = a1[col], cc = c1p[col];
#pragma unroll
    for (int r = 0; r < 4; ++r) {
      const int rl = 16 * wv + lk * 4 + r;
      float v = fmaxf(fmaf(acc[jt][r], a, cc), 0.f);
      z1h[rl * 136 + col] = __float2half(v);
    }
  }
  {
    int row = tid >> 2, seg = (tid & 3) * 16;
#pragma unroll
    for (int c = 0; c < 4; ++c)
      *(uint2*)&w2tl[row * 72 + seg + c * 4] = *(const uint2*)&w2t[row * 128 + seg + c * 4];
  }
  __syncthreads();

  f32x4 accB[4];
#pragma unroll
  for (int jt = 0; jt < 4; ++jt) {
    const float bb = b2[lrow + 16 * jt];
    f32x4 t = {bb, bb, bb, bb};
    accB[jt] = t;
  }
#pragma unroll
  for (int h = 0; h < 2; ++h) {
    if (h == 1) {
      __syncthreads();  // w2tl half-0 reads done
      int row = tid >> 2, seg = (tid & 3) * 16;
#pragma unroll
      for (int c = 0; c < 4; ++c)
        *(uint2*)&w2tl[row * 72 + seg + c * 4] = *(const uint2*)&w2t[row * 128 + 64 + seg + c * 4];
      __syncthreads();
    }
#pragma unroll
    for (int kb = 0; kb < 2; ++kb) {
      const f16x8 afB = *(const f16x8*)&z1h[(16 * wv + lrow) * 136 + h * 64 + kb * 32 + lk * 8];
#pragma unroll
      for (int jt = 0; jt < 4; ++jt) {
        const f16x8 bfB = *(const f16x8*)&w2tl[(lrow + 16 * jt) * 72 + kb * 32 + lk * 8];
        accB[jt] = __builtin_amdgcn_mfma_f32_16x16x32_f16(afB, bfB, accB[jt], 0, 0, 0);
      }
    }
  }
  // epilogue: write z2 (fp16 l<3 / fp32 l=3) + stats
#pragma unroll
  for (int jt = 0; jt < 4; ++jt) {
    const int col = lrow + 16 * jt;
    float s = 0.f, q = 0.f;
#pragma unroll
    for (int r = 0; r < 4; ++r) {
      const int rl = 16 * wv + lk * 4 + r;
      if (rl < nlim) {
        const float v = accB[jt][r];
        if (tofp16) zout16[(size_t)(nb + rl) * 64 + col] = __float2half(v);
        else zout[(size_t)(nb + rl) * 64 + col] = v;
        s += v;
        q = fmaf(v, v, q);
      }
    }
    atomicAdd(&ss[col], s);
    atomicAdd(&sq[col], q);
  }
  __syncthreads();
  if (tid < 64) {
    atomicAdd(&s2[tid], ss[tid]);
    atomicAdd(&q2[tid], sq[tid]);
  }
}

__global__ void k_finalize(const float* __restrict__ sum, const float* __restrict__ sq,
                           const float* __restrict__ g, const float* __restrict__ b,
                           float* __restrict__ a, float* __restrict__ c) {
  int j = threadIdx.x;
  const float inv = 1.0f / (float)N_NODES;
  float m = sum[j] * inv;
  float v = sq[j] * inv - m * m;
  float r = rsqrtf(v + 1e-5f);
  float aa = g[j] * r;
  a[j] = aa;
  c[j] = fmaf(-m, aa, b[j]);
}

// ---------------- pool: batch sorted -> one wave per graph, zero atomics ----
__global__ void __launch_bounds__(256)
k_pool(const float* __restrict__ z2, const float* __restrict__ a2,
       const float* __restrict__ c2, const int* __restrict__ batch,
       float* __restrict__ out) {
  int g = blockIdx.x * 4 + (threadIdx.x >> 6);
  int d = threadIdx.x & 63;
  int a = 0, b = N_NODES;
  while (a < b) { int m = (a + b) >> 1; if (batch[m] < g) a = m + 1; else b = m; }
  const int lo = a;
  b = N_NODES;
  while (a < b) { int m = (a + b) >> 1; if (batch[m] < g + 1) a = m + 1; else b = m; }
  const int hi = a;
  float s0 = 0.f, s1 = 0.f, s2 = 0.f, s3 = 0.f;
  int n = lo;
  for (; n + 4 <= hi; n += 4) {
    s0 += z2[(size_t)(n + 0) * 64 + d];
    s1 += z2[(size_t)(n + 1) * 64 + d];
    s2 += z2[(size_t)(n + 2) * 64 + d];
    s3 += z2[(size_t)(n + 3) * 64 + d];
  }
  for (; n < hi; ++n) s0 += z2[(size_t)n * 64 + d];
  float S = (s0 + s1) + (s2 + s3);
  float cntf = (float)(hi - lo);
  out[g * 64 + d] = fmaf(S, a2[d], cntf * c2[d]) / (cntf + 1e-9f);
}

extern "C" void kernel_launch(void* const* d_in, const int* in_sizes, int n_in,
                              void* d_out, int out_size, void* d_ws, size_t ws_size,
                              hipStream_t stream) {
  const int* x = (const int*)d_in[0];
  const int* ea = (const int*)d_in[1];
  const int* ei = (const int*)d_in[2];
  const int* batch = (const int*)d_in[3];
  const float* atom_emb = (const float*)d_in[4];
  const float* bond_emb = (const float*)d_in[5];
  const float* W1 = (const float*)d_in[6];
  const float* g1 = (const float*)d_in[8];
  const float* be1 = (const float*)d_in[9];
  const float* W2 = (const float*)d_in[10];
  const float* b2 = (const float*)d_in[11];
  const float* eps = (const float*)d_in[12];
  const float* bn_g = (const float*)d_in[13];
  const float* bn_b = (const float*)d_in[14];

  float* w = (float*)d_ws;
  float* A = w;                                 // fp32 z2 (layer 3 only)
  __half* A16 = (__half*)w;                     // fp16 mirror, ALIASES A
  float* B = w + (size_t)N_NODES * 64;
  __half* B16 = (__half*)B;                     // z16 lives in B slot
  float* stats = B + (size_t)N_NODES * 64;      // 4x(cs|M) = 16640
  float* s2 = stats + 16640;
  float* q2 = stats + 16704;
  float* a1 = stats + 16768;
  float* c1p = stats + 16896;
  float* a2 = stats + 17024;
  float* c2 = stats + 17088;
  __half* w1t16 = (__half*)(stats + 17152);     // 8192 halves = 4096 floats
  __half* w2t16 = (__half*)(stats + 21248);     // 8192 halves
  int* ptr = (int*)(stats + 25344);             // 100001
  int* deg = ptr + (N_NODES + 1);               // 100000
  unsigned int* csr = (unsigned int*)(deg + N_NODES);  // 1.6M
  int* bs = (int*)(csr + N_EDGES);              // 391

  const int NBLK = (N_NODES + 255) / 256;   // 391
  const int NTILE = (N_NODES + 63) / 64;    // 1563
  const int NPULL = N_NODES / 32;           // 3125 (exact)
  const int NZ = NBLK;                      // 391

  hipMemsetAsync(deg, 0, N_NODES * sizeof(int), stream);

  k_atom_embed<<<N_NODES / 4, 256, 0, stream>>>(x, atom_emb, A16);

  // CSR build (once; reused across all 4 layers)
  k_hist<<<(N_EDGES + 255) / 256, 256, 0, stream>>>(ei, deg);
  k_scan1<<<NBLK, 256, 0, stream>>>(deg, bs);
  k_scan2<<<1, 512, 0, stream>>>(bs, NBLK);
  k_scan3<<<NBLK, 256, 0, stream>>>(deg, bs, ptr);
  k_fill<<<(N_EDGES + 255) / 256, 256, 0, stream>>>(ei, ea, deg, csr);

  for (int l = 0; l < NL; ++l) {
    k_pull<<<NPULL, 256, 0, stream>>>(
        A16, csr, ptr, bond_emb + (size_t)l * 1536, a2, c2, eps + l,
        (l > 0) ? 1 : 0, B16, stats);
    k_zstats<<<NZ, 256, 0, stream>>>(B16, stats);
    k_fin1<<<1, 128, 0, stream>>>(stats, W1 + (size_t)l * 8192, W2 + (size_t)l * 8192,
                                  g1 + l * 128, be1 + l * 128, a1, c1p, w1t16, w2t16);
    k_mm2<<<NTILE, 256, 0, stream>>>(
        B16, w1t16, a1, c1p, w2t16, b2 + l * 64,
        A, A16, (l < NL - 1) ? 1 : 0, s2, q2);
    k_finalize<<<1, 64, 0, stream>>>(s2, q2, bn_g + l * 64, bn_b + l * 64, a2, c2);
  }
  k_pool<<<NG / 4, 256, 0, stream>>>(A, a2, c2, batch, (float*)d_out);
}